// Round 2
// baseline (1193.375 us; speedup 1.0000x reference)
//
#include <hip/hip_runtime.h>
#include <cstdint>
#include <cstddef>

#define N_NODES 50000
#define N_EDGES 800000
#define ET (N_EDGES + N_NODES)   // edges + self loops = 850000
#define IN_DIM 256
#define HID 128
#define HEADS 3
#define HC 384                   // HEADS * HID
#define NCLS 40
#define CAP 96                   // per-node in-edge bucket capacity (Poisson(17), P(deg>=96) ~ 1e-40)

// ---------------- CSR-by-destination build (bucketed, no sort/scan) ----------------
__global__ __launch_bounds__(256) void count_scatter(const int* __restrict__ ei,
                                                     int* __restrict__ cnt,
                                                     int* __restrict__ bucket)
{
    int e = blockIdx.x * 256 + threadIdx.x;
    if (e >= ET) return;
    int s, d;
    if (e < N_EDGES) { s = ei[e]; d = ei[N_EDGES + e]; }
    else             { s = e - N_EDGES; d = s; }          // self loop
    int pos = atomicAdd(&cnt[d], 1);
    if (pos < CAP) bucket[d * CAP + pos] = s;
}

// ---------------- fp32 tiled GEMM: C[M,N] = A[M,K] @ B[K,N] ----------------
// 64x64 tile, K-step 16, 256 threads, 4x4 per thread.
__global__ __launch_bounds__(256) void gemm_f32(const float* __restrict__ A,
                                                const float* __restrict__ B,
                                                float* __restrict__ C,
                                                int M, int K, int N)
{
    __shared__ float As[16][64];
    __shared__ float Bs[16][64];
    const int tid = threadIdx.x;
    const int bm = blockIdx.y * 64;
    const int bn = blockIdx.x * 64;
    const int ar  = tid >> 2;         // 0..63 (A tile row)
    const int ak  = (tid & 3) * 4;    // 0,4,8,12 (A tile k)
    const int bk  = tid >> 4;         // 0..15 (B tile k)
    const int bn4 = (tid & 15) * 4;   // B tile col
    const int ty = tid >> 4;          // 0..15
    const int tx = tid & 15;
    const int am = bm + ar;

    float acc[4][4] = {};

    for (int ko = 0; ko < K; ko += 16) {
        float4 a4 = make_float4(0.f, 0.f, 0.f, 0.f);
        if (am < M) a4 = *reinterpret_cast<const float4*>(A + (size_t)am * K + ko + ak);
        float4 b4 = *reinterpret_cast<const float4*>(B + (size_t)(ko + bk) * N + bn + bn4);
        __syncthreads();
        As[ak + 0][ar] = a4.x;
        As[ak + 1][ar] = a4.y;
        As[ak + 2][ar] = a4.z;
        As[ak + 3][ar] = a4.w;
        *reinterpret_cast<float4*>(&Bs[bk][bn4]) = b4;
        __syncthreads();
#pragma unroll
        for (int k = 0; k < 16; ++k) {
            float4 av = *reinterpret_cast<const float4*>(&As[k][ty * 4]);
            float4 bv = *reinterpret_cast<const float4*>(&Bs[k][tx * 4]);
            acc[0][0] += av.x * bv.x; acc[0][1] += av.x * bv.y; acc[0][2] += av.x * bv.z; acc[0][3] += av.x * bv.w;
            acc[1][0] += av.y * bv.x; acc[1][1] += av.y * bv.y; acc[1][2] += av.y * bv.z; acc[1][3] += av.y * bv.w;
            acc[2][0] += av.z * bv.x; acc[2][1] += av.z * bv.y; acc[2][2] += av.z * bv.z; acc[2][3] += av.z * bv.w;
            acc[3][0] += av.w * bv.x; acc[3][1] += av.w * bv.y; acc[3][2] += av.w * bv.z; acc[3][3] += av.w * bv.w;
        }
    }
#pragma unroll
    for (int i = 0; i < 4; ++i) {
        int m = bm + ty * 4 + i;
        if (m < M) {
            float4 o = make_float4(acc[i][0], acc[i][1], acc[i][2], acc[i][3]);
            *reinterpret_cast<float4*>(C + (size_t)m * N + bn + tx * 4) = o;
        }
    }
}

// ---------------- per-(node,head) attention scores: a_src, a_dst ----------------
__global__ __launch_bounds__(256) void scores_kernel(const float* __restrict__ h,
                                                     const float* __restrict__ att_s,
                                                     const float* __restrict__ att_d,
                                                     float* __restrict__ asrc,
                                                     float* __restrict__ adst)
{
    int gid = blockIdx.x * 256 + threadIdx.x;
    int wid = gid >> 6;
    int lane = gid & 63;
    if (wid >= N_NODES * HEADS) return;
    int nd = wid / 3;
    int hd = wid - nd * 3;
    const float* hp = h + (size_t)nd * HC + hd * HID;
    float v0 = hp[lane], v1 = hp[lane + 64];
    float s = v0 * att_s[hd * HID + lane] + v1 * att_s[hd * HID + lane + 64];
    float d = v0 * att_d[hd * HID + lane] + v1 * att_d[hd * HID + lane + 64];
#pragma unroll
    for (int off = 32; off; off >>= 1) {
        s += __shfl_xor(s, off);
        d += __shfl_xor(d, off);
    }
    if (lane == 0) { asrc[wid] = s; adst[wid] = d; }
}

__device__ __forceinline__ float lrelu(float x) { return x > 0.f ? x : 0.2f * x; }

// ---------------- per-node softmax + weighted aggregation (+bias +ReLU) ----------------
// one wave per destination node
__global__ __launch_bounds__(256) void aggregate_kernel(const float* __restrict__ h,
                                                        const float* __restrict__ asrc,
                                                        const float* __restrict__ adst,
                                                        const int* __restrict__ cnt,
                                                        const int* __restrict__ bucket,
                                                        const float* __restrict__ bias,
                                                        float* __restrict__ out)
{
    int wv = threadIdx.x >> 6;
    int lane = threadIdx.x & 63;
    int nd = blockIdx.x * 4 + wv;
    if (nd >= N_NODES) return;
    int deg = cnt[nd];
    if (deg > CAP) deg = CAP;
    const int* eb = bucket + nd * CAP;
    float ad0 = adst[nd * 3 + 0], ad1 = adst[nd * 3 + 1], ad2 = adst[nd * 3 + 2];

    // phase 1a: per-head max over incoming edges
    float m0 = -1e30f, m1 = -1e30f, m2 = -1e30f;
    for (int j = lane; j < deg; j += 64) {
        int s = eb[j];
        float x0 = lrelu(asrc[s * 3 + 0] + ad0);
        float x1 = lrelu(asrc[s * 3 + 1] + ad1);
        float x2 = lrelu(asrc[s * 3 + 2] + ad2);
        m0 = fmaxf(m0, x0); m1 = fmaxf(m1, x1); m2 = fmaxf(m2, x2);
    }
#pragma unroll
    for (int off = 32; off; off >>= 1) {
        m0 = fmaxf(m0, __shfl_xor(m0, off));
        m1 = fmaxf(m1, __shfl_xor(m1, off));
        m2 = fmaxf(m2, __shfl_xor(m2, off));
    }
    // phase 1b: sum of exp
    float s0 = 0.f, s1 = 0.f, s2 = 0.f;
    for (int j = lane; j < deg; j += 64) {
        int s = eb[j];
        s0 += expf(lrelu(asrc[s * 3 + 0] + ad0) - m0);
        s1 += expf(lrelu(asrc[s * 3 + 1] + ad1) - m1);
        s2 += expf(lrelu(asrc[s * 3 + 2] + ad2) - m2);
    }
#pragma unroll
    for (int off = 32; off; off >>= 1) {
        s0 += __shfl_xor(s0, off);
        s1 += __shfl_xor(s1, off);
        s2 += __shfl_xor(s2, off);
    }
    float r0 = 1.f / (s0 + 1e-16f);
    float r1 = 1.f / (s1 + 1e-16f);
    float r2 = 1.f / (s2 + 1e-16f);

    // phase 2: weighted accumulation; lane owns channels lane+64k
    float acc[6] = {0.f, 0.f, 0.f, 0.f, 0.f, 0.f};
    for (int j = 0; j < deg; ++j) {
        int s = eb[j];
        float w0 = expf(lrelu(asrc[s * 3 + 0] + ad0) - m0) * r0;
        float w1 = expf(lrelu(asrc[s * 3 + 1] + ad1) - m1) * r1;
        float w2 = expf(lrelu(asrc[s * 3 + 2] + ad2) - m2) * r2;
        const float* hp = h + (size_t)s * HC;
        acc[0] += hp[lane +   0] * w0;
        acc[1] += hp[lane +  64] * w0;
        acc[2] += hp[lane + 128] * w1;
        acc[3] += hp[lane + 192] * w1;
        acc[4] += hp[lane + 256] * w2;
        acc[5] += hp[lane + 320] * w2;
    }
    float* op = out + (size_t)nd * HC;
#pragma unroll
    for (int k = 0; k < 6; ++k) {
        int c = lane + 64 * k;
        float o = acc[k] + bias[c];
        op[c] = o > 0.f ? o : 0.f;   // fused ReLU (both GAT layers are ReLU'd)
    }
}

// ---------------- final classifier: out[M,40] = A[M,384] @ W[384,40] + b ----------------
__global__ __launch_bounds__(256) void out_gemm(const float* __restrict__ A,
                                                const float* __restrict__ W,
                                                const float* __restrict__ b,
                                                float* __restrict__ out)
{
    int gid = blockIdx.x * 256 + threadIdx.x;
    int wid = gid >> 6;
    int lane = gid & 63;
    if (wid >= N_NODES) return;
    const float* ar = A + (size_t)wid * HC;
    if (lane < NCLS) {
        float acc = 0.f;
#pragma unroll 4
        for (int k = 0; k < HC; ++k) acc += ar[k] * W[k * NCLS + lane];
        out[(size_t)wid * NCLS + lane] = acc + b[lane];
    }
}

extern "C" void kernel_launch(void* const* d_in, const int* in_sizes, int n_in,
                              void* d_out, int out_size, void* d_ws, size_t ws_size,
                              hipStream_t stream)
{
    const float* x    = (const float*)d_in[0];
    const int*   ei   = (const int*)d_in[1];     // int32! (harness ships integer inputs as int32)
    const float* W1   = (const float*)d_in[2];
    const float* as1  = (const float*)d_in[3];
    const float* ad1  = (const float*)d_in[4];
    const float* b1   = (const float*)d_in[5];
    const float* W2   = (const float*)d_in[6];
    const float* as2  = (const float*)d_in[7];
    const float* ad2  = (const float*)d_in[8];
    const float* b2   = (const float*)d_in[9];
    const float* outW = (const float*)d_in[10];
    const float* outb = (const float*)d_in[11];
    float* out = (float*)d_out;

    // workspace layout (fp32 elements)
    float* bufH = (float*)d_ws;                      // [N, 384] h (layer input @ W)
    float* bufA = bufH + (size_t)N_NODES * HC;       // [N, 384] aggregated + relu
    float* asrc = bufA + (size_t)N_NODES * HC;       // [N, 3]
    float* adst = asrc + (size_t)N_NODES * HEADS;    // [N, 3]
    int*   cnt    = (int*)(adst + (size_t)N_NODES * HEADS);  // [N]
    int*   bucket = cnt + N_NODES;                   // [N, CAP]

    hipMemsetAsync(cnt, 0, N_NODES * sizeof(int), stream);
    count_scatter<<<(ET + 255) / 256, 256, 0, stream>>>(ei, cnt, bucket);

    dim3 g1(HC / 64, (N_NODES + 63) / 64);
    // ---- layer 1 ----
    gemm_f32<<<g1, 256, 0, stream>>>(x, W1, bufH, N_NODES, IN_DIM, HC);
    scores_kernel<<<(N_NODES * HEADS + 3) / 4, 256, 0, stream>>>(bufH, as1, ad1, asrc, adst);
    aggregate_kernel<<<(N_NODES + 3) / 4, 256, 0, stream>>>(bufH, asrc, adst, cnt, bucket, b1, bufA);
    // ---- layer 2 ----
    gemm_f32<<<g1, 256, 0, stream>>>(bufA, W2, bufH, N_NODES, HC, HC);
    scores_kernel<<<(N_NODES * HEADS + 3) / 4, 256, 0, stream>>>(bufH, as2, ad2, asrc, adst);
    aggregate_kernel<<<(N_NODES + 3) / 4, 256, 0, stream>>>(bufH, asrc, adst, cnt, bucket, b2, bufA);
    // ---- classifier ----
    out_gemm<<<(N_NODES + 3) / 4, 256, 0, stream>>>(bufA, outW, outb, out);
}

// Round 3
// 1057.602 us; speedup vs baseline: 1.1284x; 1.1284x over previous
//
#include <hip/hip_runtime.h>
#include <cstdint>
#include <cstddef>

#define N_NODES 50000
#define N_EDGES 800000
#define ET (N_EDGES + N_NODES)   // edges + self loops = 850000
#define IN_DIM 256
#define HID 128
#define HEADS 3
#define HC 384                   // HEADS * HID
#define NCLS 40
#define CAP 96                   // per-node in-edge bucket capacity (Poisson(17), P(deg>=96) ~ 1e-40)

// ---------------- CSR-by-destination build (bucketed, no sort/scan) ----------------
__global__ __launch_bounds__(256) void count_scatter(const int* __restrict__ ei,
                                                     int* __restrict__ cnt,
                                                     int* __restrict__ bucket)
{
    int e = blockIdx.x * 256 + threadIdx.x;
    if (e >= ET) return;
    int s, d;
    if (e < N_EDGES) { s = ei[e]; d = ei[N_EDGES + e]; }
    else             { s = e - N_EDGES; d = s; }          // self loop
    int pos = atomicAdd(&cnt[d], 1);
    if (pos < CAP) bucket[d * CAP + pos] = s;
}

// ---------------- fp32 tiled GEMM: C[M,N] = A[M,K] @ B[K,N] ----------------
// 64x64 tile, K-step 16, 256 threads, 4x4 per thread.
__global__ __launch_bounds__(256) void gemm_f32(const float* __restrict__ A,
                                                const float* __restrict__ B,
                                                float* __restrict__ C,
                                                int M, int K, int N)
{
    __shared__ float As[16][64];
    __shared__ float Bs[16][64];
    const int tid = threadIdx.x;
    const int bm = blockIdx.y * 64;
    const int bn = blockIdx.x * 64;
    const int ar  = tid >> 2;         // 0..63 (A tile row)
    const int ak  = (tid & 3) * 4;    // 0,4,8,12 (A tile k)
    const int bk  = tid >> 4;         // 0..15 (B tile k)
    const int bn4 = (tid & 15) * 4;   // B tile col
    const int ty = tid >> 4;          // 0..15
    const int tx = tid & 15;
    const int am = bm + ar;

    float acc[4][4] = {};

    for (int ko = 0; ko < K; ko += 16) {
        float4 a4 = make_float4(0.f, 0.f, 0.f, 0.f);
        if (am < M) a4 = *reinterpret_cast<const float4*>(A + (size_t)am * K + ko + ak);
        float4 b4 = *reinterpret_cast<const float4*>(B + (size_t)(ko + bk) * N + bn + bn4);
        __syncthreads();
        As[ak + 0][ar] = a4.x;
        As[ak + 1][ar] = a4.y;
        As[ak + 2][ar] = a4.z;
        As[ak + 3][ar] = a4.w;
        *reinterpret_cast<float4*>(&Bs[bk][bn4]) = b4;
        __syncthreads();
#pragma unroll
        for (int k = 0; k < 16; ++k) {
            float4 av = *reinterpret_cast<const float4*>(&As[k][ty * 4]);
            float4 bv = *reinterpret_cast<const float4*>(&Bs[k][tx * 4]);
            acc[0][0] += av.x * bv.x; acc[0][1] += av.x * bv.y; acc[0][2] += av.x * bv.z; acc[0][3] += av.x * bv.w;
            acc[1][0] += av.y * bv.x; acc[1][1] += av.y * bv.y; acc[1][2] += av.y * bv.z; acc[1][3] += av.y * bv.w;
            acc[2][0] += av.z * bv.x; acc[2][1] += av.z * bv.y; acc[2][2] += av.z * bv.z; acc[2][3] += av.z * bv.w;
            acc[3][0] += av.w * bv.x; acc[3][1] += av.w * bv.y; acc[3][2] += av.w * bv.z; acc[3][3] += av.w * bv.w;
        }
    }
#pragma unroll
    for (int i = 0; i < 4; ++i) {
        int m = bm + ty * 4 + i;
        if (m < M) {
            float4 o = make_float4(acc[i][0], acc[i][1], acc[i][2], acc[i][3]);
            *reinterpret_cast<float4*>(C + (size_t)m * N + bn + tx * 4) = o;
        }
    }
}

// ---------------- per-(node,head) attention scores: a_src, a_dst ----------------
__global__ __launch_bounds__(256) void scores_kernel(const float* __restrict__ h,
                                                     const float* __restrict__ att_s,
                                                     const float* __restrict__ att_d,
                                                     float* __restrict__ asrc,
                                                     float* __restrict__ adst)
{
    int gid = blockIdx.x * 256 + threadIdx.x;
    int wid = gid >> 6;
    int lane = gid & 63;
    if (wid >= N_NODES * HEADS) return;
    int nd = wid / 3;
    int hd = wid - nd * 3;
    const float* hp = h + (size_t)nd * HC + hd * HID;
    float v0 = hp[lane], v1 = hp[lane + 64];
    float s = v0 * att_s[hd * HID + lane] + v1 * att_s[hd * HID + lane + 64];
    float d = v0 * att_d[hd * HID + lane] + v1 * att_d[hd * HID + lane + 64];
#pragma unroll
    for (int off = 32; off; off >>= 1) {
        s += __shfl_xor(s, off);
        d += __shfl_xor(d, off);
    }
    if (lane == 0) { asrc[wid] = s; adst[wid] = d; }
}

__device__ __forceinline__ float lrelu(float x) { return x > 0.f ? x : 0.2f * x; }

// ---------------- per-node softmax + weighted aggregation (+bias +ReLU) ----------------
// one wave per destination node
__global__ __launch_bounds__(256) void aggregate_kernel(const float* __restrict__ h,
                                                        const float* __restrict__ asrc,
                                                        const float* __restrict__ adst,
                                                        const int* __restrict__ cnt,
                                                        const int* __restrict__ bucket,
                                                        const float* __restrict__ bias,
                                                        float* __restrict__ out)
{
    int wv = threadIdx.x >> 6;
    int lane = threadIdx.x & 63;
    int nd = blockIdx.x * 4 + wv;
    if (nd >= N_NODES) return;
    int deg = cnt[nd];
    if (deg > CAP) deg = CAP;
    const int* eb = bucket + nd * CAP;
    float ad0 = adst[nd * 3 + 0], ad1 = adst[nd * 3 + 1], ad2 = adst[nd * 3 + 2];

    // phase 1a: per-head max over incoming edges
    float m0 = -1e30f, m1 = -1e30f, m2 = -1e30f;
    for (int j = lane; j < deg; j += 64) {
        int s = eb[j];
        float x0 = lrelu(asrc[s * 3 + 0] + ad0);
        float x1 = lrelu(asrc[s * 3 + 1] + ad1);
        float x2 = lrelu(asrc[s * 3 + 2] + ad2);
        m0 = fmaxf(m0, x0); m1 = fmaxf(m1, x1); m2 = fmaxf(m2, x2);
    }
#pragma unroll
    for (int off = 32; off; off >>= 1) {
        m0 = fmaxf(m0, __shfl_xor(m0, off));
        m1 = fmaxf(m1, __shfl_xor(m1, off));
        m2 = fmaxf(m2, __shfl_xor(m2, off));
    }
    // phase 1b: sum of exp
    float s0 = 0.f, s1 = 0.f, s2 = 0.f;
    for (int j = lane; j < deg; j += 64) {
        int s = eb[j];
        s0 += expf(lrelu(asrc[s * 3 + 0] + ad0) - m0);
        s1 += expf(lrelu(asrc[s * 3 + 1] + ad1) - m1);
        s2 += expf(lrelu(asrc[s * 3 + 2] + ad2) - m2);
    }
#pragma unroll
    for (int off = 32; off; off >>= 1) {
        s0 += __shfl_xor(s0, off);
        s1 += __shfl_xor(s1, off);
        s2 += __shfl_xor(s2, off);
    }
    float r0 = 1.f / (s0 + 1e-16f);
    float r1 = 1.f / (s1 + 1e-16f);
    float r2 = 1.f / (s2 + 1e-16f);

    // phase 2: weighted accumulation; lane owns channels lane+64k
    float acc[6] = {0.f, 0.f, 0.f, 0.f, 0.f, 0.f};
    for (int j = 0; j < deg; ++j) {
        int s = eb[j];
        float w0 = expf(lrelu(asrc[s * 3 + 0] + ad0) - m0) * r0;
        float w1 = expf(lrelu(asrc[s * 3 + 1] + ad1) - m1) * r1;
        float w2 = expf(lrelu(asrc[s * 3 + 2] + ad2) - m2) * r2;
        const float* hp = h + (size_t)s * HC;
        acc[0] += hp[lane +   0] * w0;
        acc[1] += hp[lane +  64] * w0;
        acc[2] += hp[lane + 128] * w1;
        acc[3] += hp[lane + 192] * w1;
        acc[4] += hp[lane + 256] * w2;
        acc[5] += hp[lane + 320] * w2;
    }
    float* op = out + (size_t)nd * HC;
#pragma unroll
    for (int k = 0; k < 6; ++k) {
        int c = lane + 64 * k;
        float o = acc[k] + bias[c];
        op[c] = o > 0.f ? o : 0.f;   // fused ReLU (both GAT layers are ReLU'd)
    }
}

// ---------------- final classifier: out[M,40] = A[M,384] @ W[384,40] + b ----------------
// register-blocked: thread = (row, 4-col chunk); k vectorized by 4.
// 10 threads per row -> A float4 loads are wave-broadcast, W loads coalesced.
__global__ __launch_bounds__(256) void out_gemm(const float* __restrict__ A,
                                                const float* __restrict__ W,
                                                const float* __restrict__ b,
                                                float* __restrict__ out)
{
    int gid = blockIdx.x * 256 + threadIdx.x;
    int r  = gid / 10;
    int c4 = (gid - r * 10) * 4;
    if (r >= N_NODES) return;
    const float* ar = A + (size_t)r * HC;
    float ax = 0.f, ay = 0.f, az = 0.f, aw = 0.f;
#pragma unroll 2
    for (int k = 0; k < HC; k += 4) {
        float4 a  = *reinterpret_cast<const float4*>(ar + k);
        float4 w0 = *reinterpret_cast<const float4*>(W + (size_t)(k + 0) * NCLS + c4);
        float4 w1 = *reinterpret_cast<const float4*>(W + (size_t)(k + 1) * NCLS + c4);
        float4 w2 = *reinterpret_cast<const float4*>(W + (size_t)(k + 2) * NCLS + c4);
        float4 w3 = *reinterpret_cast<const float4*>(W + (size_t)(k + 3) * NCLS + c4);
        ax += a.x * w0.x + a.y * w1.x + a.z * w2.x + a.w * w3.x;
        ay += a.x * w0.y + a.y * w1.y + a.z * w2.y + a.w * w3.y;
        az += a.x * w0.z + a.y * w1.z + a.z * w2.z + a.w * w3.z;
        aw += a.x * w0.w + a.y * w1.w + a.z * w2.w + a.w * w3.w;
    }
    float4 bb = *reinterpret_cast<const float4*>(b + c4);
    float4 o = make_float4(ax + bb.x, ay + bb.y, az + bb.z, aw + bb.w);
    *reinterpret_cast<float4*>(out + (size_t)r * NCLS + c4) = o;
}

extern "C" void kernel_launch(void* const* d_in, const int* in_sizes, int n_in,
                              void* d_out, int out_size, void* d_ws, size_t ws_size,
                              hipStream_t stream)
{
    const float* x    = (const float*)d_in[0];
    const int*   ei   = (const int*)d_in[1];     // int32 (harness ships integer inputs as int32)
    const float* W1   = (const float*)d_in[2];
    const float* as1  = (const float*)d_in[3];
    const float* ad1  = (const float*)d_in[4];
    const float* b1   = (const float*)d_in[5];
    const float* W2   = (const float*)d_in[6];
    const float* as2  = (const float*)d_in[7];
    const float* ad2  = (const float*)d_in[8];
    const float* b2   = (const float*)d_in[9];
    const float* outW = (const float*)d_in[10];
    const float* outb = (const float*)d_in[11];
    float* out = (float*)d_out;

    // workspace layout (fp32 elements)
    float* bufH = (float*)d_ws;                      // [N, 384] h (layer input @ W)
    float* bufA = bufH + (size_t)N_NODES * HC;       // [N, 384] aggregated + relu
    float* asrc = bufA + (size_t)N_NODES * HC;       // [N, 3]
    float* adst = asrc + (size_t)N_NODES * HEADS;    // [N, 3]
    int*   cnt    = (int*)(adst + (size_t)N_NODES * HEADS);  // [N]
    int*   bucket = cnt + N_NODES;                   // [N, CAP]

    hipMemsetAsync(cnt, 0, N_NODES * sizeof(int), stream);
    count_scatter<<<(ET + 255) / 256, 256, 0, stream>>>(ei, cnt, bucket);

    dim3 g1(HC / 64, (N_NODES + 63) / 64);
    // ---- layer 1 ----
    gemm_f32<<<g1, 256, 0, stream>>>(x, W1, bufH, N_NODES, IN_DIM, HC);
    scores_kernel<<<(N_NODES * HEADS + 3) / 4, 256, 0, stream>>>(bufH, as1, ad1, asrc, adst);
    aggregate_kernel<<<(N_NODES + 3) / 4, 256, 0, stream>>>(bufH, asrc, adst, cnt, bucket, b1, bufA);
    // ---- layer 2 ----
    gemm_f32<<<g1, 256, 0, stream>>>(bufA, W2, bufH, N_NODES, HC, HC);
    scores_kernel<<<(N_NODES * HEADS + 3) / 4, 256, 0, stream>>>(bufH, as2, ad2, asrc, adst);
    aggregate_kernel<<<(N_NODES + 3) / 4, 256, 0, stream>>>(bufH, asrc, adst, cnt, bucket, b2, bufA);
    // ---- classifier ----
    out_gemm<<<(N_NODES * 10 + 255) / 256, 256, 0, stream>>>(bufA, outW, outb, out);
}

// Round 4
// 906.974 us; speedup vs baseline: 1.3158x; 1.1661x over previous
//
#include <hip/hip_runtime.h>
#include <cstdint>
#include <cstddef>

typedef unsigned short u16;
typedef unsigned int   u32;
typedef __attribute__((ext_vector_type(8))) short bf16x8;
typedef __attribute__((ext_vector_type(4))) float f32x4;

#define N_NODES 50000
#define N_EDGES 800000
#define ET (N_EDGES + N_NODES)   // edges + self loops = 850000
#define IN_DIM 256
#define HID 128
#define HEADS 3
#define HC 384                   // HEADS * HID
#define NCLS 40
#define CAP 96                   // per-node in-edge bucket capacity (Poisson(17), P(deg>=96) ~ 1e-40)

// ---------------- bf16 helpers (RNE) ----------------
__device__ __forceinline__ u16 f2bf(float f) {
    union { float f; u32 u; } x; x.f = f;
    u32 r = x.u + 0x7fffu + ((x.u >> 16) & 1u);
    return (u16)(r >> 16);
}
__device__ __forceinline__ float bf2f(u16 b) {
    union { u32 u; float f; } x; x.u = ((u32)b) << 16; return x.f;
}

__device__ __forceinline__ void gload_lds16(const void* g, void* l) {
    __builtin_amdgcn_global_load_lds((const __attribute__((address_space(1))) void*)g,
                                     (__attribute__((address_space(3))) void*)l, 16, 0, 0);
}

// ---------------- CSR-by-destination build (bucketed, no sort/scan) ----------------
__global__ __launch_bounds__(256) void count_scatter(const int* __restrict__ ei,
                                                     int* __restrict__ cnt,
                                                     int* __restrict__ bucket)
{
    int e = blockIdx.x * 256 + threadIdx.x;
    if (e >= ET) return;
    int s, d;
    if (e < N_EDGES) { s = ei[e]; d = ei[N_EDGES + e]; }
    else             { s = e - N_EDGES; d = s; }          // self loop
    int pos = atomicAdd(&cnt[d], 1);
    if (pos < CAP) bucket[d * CAP + pos] = s;
}

// ---------------- fp32 -> (hi,lo) bf16 split, flat, 4 elems/thread ----------------
__global__ __launch_bounds__(256) void split_kernel(const float* __restrict__ in,
                                                    u16* __restrict__ hi,
                                                    u16* __restrict__ lo, int n4)
{
    int i = blockIdx.x * 256 + threadIdx.x;
    if (i >= n4) return;
    float4 v = reinterpret_cast<const float4*>(in)[i];
    ushort4 h, l;
    h.x = f2bf(v.x); l.x = f2bf(v.x - bf2f(h.x));
    h.y = f2bf(v.y); l.y = f2bf(v.y - bf2f(h.y));
    h.z = f2bf(v.z); l.z = f2bf(v.z - bf2f(h.z));
    h.w = f2bf(v.w); l.w = f2bf(v.w - bf2f(h.w));
    reinterpret_cast<ushort4*>(hi)[i] = h;
    reinterpret_cast<ushort4*>(lo)[i] = l;
}

// ---------------- W[K][N] -> transposed split Wt{h,l}[N][K] ----------------
__global__ __launch_bounds__(256) void split_wt(const float* __restrict__ W,
                                                u16* __restrict__ WtH,
                                                u16* __restrict__ WtL, int K)
{
    int idx = blockIdx.x * 256 + threadIdx.x;
    if (idx >= K * HC) return;
    int k = idx / HC, n = idx - k * HC;
    float v = W[idx];
    u16 h = f2bf(v);
    WtH[(size_t)n * K + k] = h;
    WtL[(size_t)n * K + k] = f2bf(v - bf2f(h));
}

// ---------------- split-bf16 MFMA GEMM: C[M,HC] = A[M,K] @ Wt[HC,K]^T ----------------
// A given as Ah/Al bf16 [M][K]; B as Bh/Bl bf16 [N=HC][K] (transposed weights).
// 128x128 tile, BK=32, 4 waves in 2x2, each wave 64x64 (4x4 frags of 16x16x32).
// acc += Ah*Bh + Al*Bh + Ah*Bl  (split-fp32 precision; Al*Bl term negligible).
#define BM 128
#define BN 128
#define BK 32
__global__ __launch_bounds__(256) void gemm_mfma(const u16* __restrict__ Ah, const u16* __restrict__ Al,
                                                 const u16* __restrict__ Bh, const u16* __restrict__ Bl,
                                                 float* __restrict__ C, int M, int K)
{
    // LDS tile layout [kgrp][row][8] (kgrp = k/8): frag ds_read_b128 is the canonical
    // contiguous pattern (conflict-free); global_load_lds dest stays linear, the
    // chunk->row/kgrp remap is applied to the GLOBAL source address (rule #21).
    __shared__ u16 sAh[BM * BK], sAl[BM * BK], sBh[BM * BK], sBl[BM * BK];
    const int tid = threadIdx.x;
    const int ln  = tid & 63;
    const int wv  = tid >> 6;
    const int bm  = blockIdx.y * BM;
    const int bn  = blockIdx.x * BN;
    const int wm  = (wv >> 1) * 64;
    const int wn  = (wv & 1) * 64;

    f32x4 acc[4][4] = {};

    const int nK = K >> 5;   // K-steps of 32
    for (int kt = 0; kt < nK; ++kt) {
        const int ko = kt * BK;
        __syncthreads();     // all waves done reading previous tiles
#pragma unroll
        for (int rnd = 0; rnd < 2; ++rnd) {
            // chunk c (16B) -> lds element c*8; c = kg*128 + row  ([kgrp][row][8] layout)
            int c   = rnd * 256 + wv * 64 + ln;
            int row = c & 127;
            int kg  = c >> 7;
            int ldsOff = (rnd * 256 + wv * 64) * 8;  // wave-uniform base (u16 elems)
            int ar = bm + row; if (ar >= M) ar = M - 1;      // clamp M edge
            size_t aOff = (size_t)ar * K + ko + kg * 8;
            gload_lds16(Ah + aOff, sAh + ldsOff);
            gload_lds16(Al + aOff, sAl + ldsOff);
            size_t bOff = (size_t)(bn + row) * K + ko + kg * 8;
            gload_lds16(Bh + bOff, sBh + ldsOff);
            gload_lds16(Bl + bOff, sBl + ldsOff);
        }
        __syncthreads();     // drains vmcnt, LDS visible

        const int kg = ln >> 4;
        const int lr = ln & 15;
        bf16x8 bhf[4], blf[4];
#pragma unroll
        for (int ni = 0; ni < 4; ++ni) {
            int off = kg * (128 * 8) + (wn + ni * 16 + lr) * 8;
            bhf[ni] = *reinterpret_cast<const bf16x8*>(sBh + off);
            blf[ni] = *reinterpret_cast<const bf16x8*>(sBl + off);
        }
#pragma unroll
        for (int mi = 0; mi < 4; ++mi) {
            int off = kg * (128 * 8) + (wm + mi * 16 + lr) * 8;
            bf16x8 ah = *reinterpret_cast<const bf16x8*>(sAh + off);
            bf16x8 al = *reinterpret_cast<const bf16x8*>(sAl + off);
#pragma unroll
            for (int ni = 0; ni < 4; ++ni) {
                acc[mi][ni] = __builtin_amdgcn_mfma_f32_16x16x32_bf16(ah, bhf[ni], acc[mi][ni], 0, 0, 0);
                acc[mi][ni] = __builtin_amdgcn_mfma_f32_16x16x32_bf16(al, bhf[ni], acc[mi][ni], 0, 0, 0);
                acc[mi][ni] = __builtin_amdgcn_mfma_f32_16x16x32_bf16(ah, blf[ni], acc[mi][ni], 0, 0, 0);
            }
        }
    }

    // C/D layout (m89-verified): col = lane&15, row = (lane>>4)*4 + i
    const int lr = ln & 15;
    const int lg = ln >> 4;
#pragma unroll
    for (int mi = 0; mi < 4; ++mi) {
#pragma unroll
        for (int i = 0; i < 4; ++i) {
            int r = bm + wm + mi * 16 + lg * 4 + i;
            if (r < M) {
#pragma unroll
                for (int ni = 0; ni < 4; ++ni) {
                    C[(size_t)r * HC + bn + wn + ni * 16 + lr] = acc[mi][ni][i];
                }
            }
        }
    }
}

// ---------------- per-(node,head) attention scores: a_src, a_dst ----------------
__global__ __launch_bounds__(256) void scores_kernel(const float* __restrict__ h,
                                                     const float* __restrict__ att_s,
                                                     const float* __restrict__ att_d,
                                                     float* __restrict__ asrc,
                                                     float* __restrict__ adst)
{
    int gid = blockIdx.x * 256 + threadIdx.x;
    int wid = gid >> 6;
    int lane = gid & 63;
    if (wid >= N_NODES * HEADS) return;
    int nd = wid / 3;
    int hd = wid - nd * 3;
    const float* hp = h + (size_t)nd * HC + hd * HID;
    float v0 = hp[lane], v1 = hp[lane + 64];
    float s = v0 * att_s[hd * HID + lane] + v1 * att_s[hd * HID + lane + 64];
    float d = v0 * att_d[hd * HID + lane] + v1 * att_d[hd * HID + lane + 64];
#pragma unroll
    for (int off = 32; off; off >>= 1) {
        s += __shfl_xor(s, off);
        d += __shfl_xor(d, off);
    }
    if (lane == 0) { asrc[wid] = s; adst[wid] = d; }
}

__device__ __forceinline__ float lrelu(float x) { return x > 0.f ? x : 0.2f * x; }

// ---------------- per-node softmax + weighted aggregation (+bias +ReLU) ----------------
// one wave per destination node; output either fp32 (fOut) or split bf16 (hOut/lOut)
__global__ __launch_bounds__(256) void aggregate_kernel(const float* __restrict__ h,
                                                        const float* __restrict__ asrc,
                                                        const float* __restrict__ adst,
                                                        const int* __restrict__ cnt,
                                                        const int* __restrict__ bucket,
                                                        const float* __restrict__ bias,
                                                        u16* __restrict__ hOut,
                                                        u16* __restrict__ lOut,
                                                        float* __restrict__ fOut)
{
    int wv = threadIdx.x >> 6;
    int lane = threadIdx.x & 63;
    int nd = blockIdx.x * 4 + wv;
    if (nd >= N_NODES) return;
    int deg = cnt[nd];
    if (deg > CAP) deg = CAP;
    const int* eb = bucket + nd * CAP;
    float ad0 = adst[nd * 3 + 0], ad1 = adst[nd * 3 + 1], ad2 = adst[nd * 3 + 2];

    float m0 = -1e30f, m1 = -1e30f, m2 = -1e30f;
    for (int j = lane; j < deg; j += 64) {
        int s = eb[j];
        m0 = fmaxf(m0, lrelu(asrc[s * 3 + 0] + ad0));
        m1 = fmaxf(m1, lrelu(asrc[s * 3 + 1] + ad1));
        m2 = fmaxf(m2, lrelu(asrc[s * 3 + 2] + ad2));
    }
#pragma unroll
    for (int off = 32; off; off >>= 1) {
        m0 = fmaxf(m0, __shfl_xor(m0, off));
        m1 = fmaxf(m1, __shfl_xor(m1, off));
        m2 = fmaxf(m2, __shfl_xor(m2, off));
    }
    float s0 = 0.f, s1 = 0.f, s2 = 0.f;
    for (int j = lane; j < deg; j += 64) {
        int s = eb[j];
        s0 += expf(lrelu(asrc[s * 3 + 0] + ad0) - m0);
        s1 += expf(lrelu(asrc[s * 3 + 1] + ad1) - m1);
        s2 += expf(lrelu(asrc[s * 3 + 2] + ad2) - m2);
    }
#pragma unroll
    for (int off = 32; off; off >>= 1) {
        s0 += __shfl_xor(s0, off);
        s1 += __shfl_xor(s1, off);
        s2 += __shfl_xor(s2, off);
    }
    float r0 = 1.f / (s0 + 1e-16f);
    float r1 = 1.f / (s1 + 1e-16f);
    float r2 = 1.f / (s2 + 1e-16f);

    float acc[6] = {0.f, 0.f, 0.f, 0.f, 0.f, 0.f};
    for (int j = 0; j < deg; ++j) {
        int s = eb[j];
        float w0 = expf(lrelu(asrc[s * 3 + 0] + ad0) - m0) * r0;
        float w1 = expf(lrelu(asrc[s * 3 + 1] + ad1) - m1) * r1;
        float w2 = expf(lrelu(asrc[s * 3 + 2] + ad2) - m2) * r2;
        const float* hp = h + (size_t)s * HC;
        acc[0] += hp[lane +   0] * w0;
        acc[1] += hp[lane +  64] * w0;
        acc[2] += hp[lane + 128] * w1;
        acc[3] += hp[lane + 192] * w1;
        acc[4] += hp[lane + 256] * w2;
        acc[5] += hp[lane + 320] * w2;
    }
#pragma unroll
    for (int k = 0; k < 6; ++k) {
        int c = lane + 64 * k;
        float o = acc[k] + bias[c];
        o = o > 0.f ? o : 0.f;             // fused ReLU
        size_t idx = (size_t)nd * HC + c;
        if (fOut) {
            fOut[idx] = o;
        } else {
            u16 hb = f2bf(o);
            hOut[idx] = hb;
            lOut[idx] = f2bf(o - bf2f(hb));
        }
    }
}

// ---------------- final classifier: out[M,40] = A[M,384] @ W[384,40] + b ----------------
__global__ __launch_bounds__(256) void out_gemm(const float* __restrict__ A,
                                                const float* __restrict__ W,
                                                const float* __restrict__ b,
                                                float* __restrict__ out)
{
    int gid = blockIdx.x * 256 + threadIdx.x;
    int r  = gid / 10;
    int c4 = (gid - r * 10) * 4;
    if (r >= N_NODES) return;
    const float* ar = A + (size_t)r * HC;
    float ax = 0.f, ay = 0.f, az = 0.f, aw = 0.f;
#pragma unroll 2
    for (int k = 0; k < HC; k += 4) {
        float4 a  = *reinterpret_cast<const float4*>(ar + k);
        float4 w0 = *reinterpret_cast<const float4*>(W + (size_t)(k + 0) * NCLS + c4);
        float4 w1 = *reinterpret_cast<const float4*>(W + (size_t)(k + 1) * NCLS + c4);
        float4 w2 = *reinterpret_cast<const float4*>(W + (size_t)(k + 2) * NCLS + c4);
        float4 w3 = *reinterpret_cast<const float4*>(W + (size_t)(k + 3) * NCLS + c4);
        ax += a.x * w0.x + a.y * w1.x + a.z * w2.x + a.w * w3.x;
        ay += a.x * w0.y + a.y * w1.y + a.z * w2.y + a.w * w3.y;
        az += a.x * w0.z + a.y * w1.z + a.z * w2.z + a.w * w3.z;
        aw += a.x * w0.w + a.y * w1.w + a.z * w2.w + a.w * w3.w;
    }
    float4 bb = *reinterpret_cast<const float4*>(b + c4);
    float4 o = make_float4(ax + bb.x, ay + bb.y, az + bb.z, aw + bb.w);
    *reinterpret_cast<float4*>(out + (size_t)r * NCLS + c4) = o;
}

extern "C" void kernel_launch(void* const* d_in, const int* in_sizes, int n_in,
                              void* d_out, int out_size, void* d_ws, size_t ws_size,
                              hipStream_t stream)
{
    const float* x    = (const float*)d_in[0];
    const int*   ei   = (const int*)d_in[1];     // int32 (harness ships integer inputs as int32)
    const float* W1   = (const float*)d_in[2];
    const float* as1  = (const float*)d_in[3];
    const float* ad1  = (const float*)d_in[4];
    const float* b1   = (const float*)d_in[5];
    const float* W2   = (const float*)d_in[6];
    const float* as2  = (const float*)d_in[7];
    const float* ad2  = (const float*)d_in[8];
    const float* b2   = (const float*)d_in[9];
    const float* outW = (const float*)d_in[10];
    const float* outb = (const float*)d_in[11];
    float* out = (float*)d_out;

    // ---- workspace layout ----
    // bufH: [N,384] fp32 (gemm output, both layers)            76.8 MB
    // region2 (76.8 MB), lifetimes disjoint:
    //   xh/xl   bf16 [N,256] each   (dead after gemm1)
    //   aggH/aggL bf16 [N,384] each (written by agg1, dead after gemm2)
    //   bufA    fp32 [N,384]        (written by agg2, read by out_gemm)
    float* bufH = (float*)d_ws;
    char*  reg2 = (char*)(bufH + (size_t)N_NODES * HC);
    u16*   xh   = (u16*)reg2;
    u16*   xl   = xh + (size_t)N_NODES * IN_DIM;
    u16*   aggH = (u16*)reg2;
    u16*   aggL = aggH + (size_t)N_NODES * HC;
    float* bufA = (float*)reg2;
    char*  tail = reg2 + (size_t)N_NODES * HC * 4;
    u16* W1tH = (u16*)tail;                         // [384][256]
    u16* W1tL = W1tH + (size_t)IN_DIM * HC;
    u16* W2tH = W1tL + (size_t)IN_DIM * HC;         // [384][384]
    u16* W2tL = W2tH + (size_t)HC * HC;
    float* asrc = (float*)(W2tL + (size_t)HC * HC);
    float* adst = asrc + (size_t)N_NODES * HEADS;
    int*   cnt    = (int*)(adst + (size_t)N_NODES * HEADS);
    int*   bucket = cnt + N_NODES;

    hipMemsetAsync(cnt, 0, N_NODES * sizeof(int), stream);
    count_scatter<<<(ET + 255) / 256, 256, 0, stream>>>(ei, cnt, bucket);

    // split inputs/weights to (hi,lo) bf16
    split_kernel<<<(N_NODES * IN_DIM / 4 + 255) / 256, 256, 0, stream>>>(x, xh, xl, N_NODES * IN_DIM / 4);
    split_wt<<<(IN_DIM * HC + 255) / 256, 256, 0, stream>>>(W1, W1tH, W1tL, IN_DIM);
    split_wt<<<(HC * HC + 255) / 256, 256, 0, stream>>>(W2, W2tH, W2tL, HC);

    dim3 gg(HC / BN, (N_NODES + BM - 1) / BM);   // (3, 391)
    // ---- layer 1 ----
    gemm_mfma<<<gg, 256, 0, stream>>>(xh, xl, W1tH, W1tL, bufH, N_NODES, IN_DIM);
    scores_kernel<<<(N_NODES * HEADS + 3) / 4, 256, 0, stream>>>(bufH, as1, ad1, asrc, adst);
    aggregate_kernel<<<(N_NODES + 3) / 4, 256, 0, stream>>>(bufH, asrc, adst, cnt, bucket, b1,
                                                            aggH, aggL, nullptr);
    // ---- layer 2 ----
    gemm_mfma<<<gg, 256, 0, stream>>>(aggH, aggL, W2tH, W2tL, bufH, N_NODES, HC);
    scores_kernel<<<(N_NODES * HEADS + 3) / 4, 256, 0, stream>>>(bufH, as2, ad2, asrc, adst);
    aggregate_kernel<<<(N_NODES + 3) / 4, 256, 0, stream>>>(bufH, asrc, adst, cnt, bucket, b2,
                                                            nullptr, nullptr, bufA);
    // ---- classifier ----
    out_gemm<<<(N_NODES * 10 + 255) / 256, 256, 0, stream>>>(bufA, outW, outb, out);
}

// Round 5
// 880.168 us; speedup vs baseline: 1.3558x; 1.0305x over previous
//
#include <hip/hip_runtime.h>
#include <cstdint>
#include <cstddef>

typedef unsigned short u16;
typedef unsigned int   u32;
typedef __attribute__((ext_vector_type(8))) short bf16x8;
typedef __attribute__((ext_vector_type(4))) float f32x4;

#define N_NODES 50000
#define N_EDGES 800000
#define ET (N_EDGES + N_NODES)   // edges + self loops = 850000
#define IN_DIM 256
#define HID 128
#define HEADS 3
#define HC 384                   // HEADS * HID
#define NCLS 40
#define CAP 96                   // per-node in-edge bucket capacity (deg ~ Poisson(17), max@50K nodes ~45)

// ---------------- bf16 helpers (RNE) ----------------
__device__ __forceinline__ u16 f2bf(float f) {
    union { float f; u32 u; } x; x.f = f;
    u32 r = x.u + 0x7fffu + ((x.u >> 16) & 1u);
    return (u16)(r >> 16);
}
__device__ __forceinline__ float bf2f(u16 b) {
    union { u32 u; float f; } x; x.u = ((u32)b) << 16; return x.f;
}

__device__ __forceinline__ void gload_lds16(const void* g, void* l) {
    __builtin_amdgcn_global_load_lds((const __attribute__((address_space(1))) void*)g,
                                     (__attribute__((address_space(3))) void*)l, 16, 0, 0);
}

__device__ __forceinline__ float rdlane_f(float v, int l) {
    return __int_as_float(__builtin_amdgcn_readlane(__float_as_int(v), l));
}

// ---------------- CSR-by-destination build (bucketed, no sort/scan) ----------------
__global__ __launch_bounds__(256) void count_scatter(const int* __restrict__ ei,
                                                     int* __restrict__ cnt,
                                                     int* __restrict__ bucket)
{
    int e = blockIdx.x * 256 + threadIdx.x;
    if (e >= ET) return;
    int s, d;
    if (e < N_EDGES) { s = ei[e]; d = ei[N_EDGES + e]; }
    else             { s = e - N_EDGES; d = s; }          // self loop
    int pos = atomicAdd(&cnt[d], 1);
    if (pos < CAP) bucket[d * CAP + pos] = s;
}

// ---------------- fp32 -> (hi,lo) bf16 split, flat, 4 elems/thread ----------------
__global__ __launch_bounds__(256) void split_kernel(const float* __restrict__ in,
                                                    u16* __restrict__ hi,
                                                    u16* __restrict__ lo, int n4)
{
    int i = blockIdx.x * 256 + threadIdx.x;
    if (i >= n4) return;
    float4 v = reinterpret_cast<const float4*>(in)[i];
    ushort4 h, l;
    h.x = f2bf(v.x); l.x = f2bf(v.x - bf2f(h.x));
    h.y = f2bf(v.y); l.y = f2bf(v.y - bf2f(h.y));
    h.z = f2bf(v.z); l.z = f2bf(v.z - bf2f(h.z));
    h.w = f2bf(v.w); l.w = f2bf(v.w - bf2f(h.w));
    reinterpret_cast<ushort4*>(hi)[i] = h;
    reinterpret_cast<ushort4*>(lo)[i] = l;
}

// ---------------- W[K][N] -> transposed split Wt{h,l}[N][K] ----------------
__global__ __launch_bounds__(256) void split_wt(const float* __restrict__ W,
                                                u16* __restrict__ WtH,
                                                u16* __restrict__ WtL, int K)
{
    int idx = blockIdx.x * 256 + threadIdx.x;
    if (idx >= K * HC) return;
    int k = idx / HC, n = idx - k * HC;
    float v = W[idx];
    u16 h = f2bf(v);
    WtH[(size_t)n * K + k] = h;
    WtL[(size_t)n * K + k] = f2bf(v - bf2f(h));
}

// ---------------- split-bf16 MFMA GEMM: C[M,HC] = A[M,K] @ Wt[HC,K]^T ----------------
#define BM 128
#define BN 128
#define BK 32
__global__ __launch_bounds__(256) void gemm_mfma(const u16* __restrict__ Ah, const u16* __restrict__ Al,
                                                 const u16* __restrict__ Bh, const u16* __restrict__ Bl,
                                                 float* __restrict__ C, int M, int K)
{
    __shared__ u16 sAh[BM * BK], sAl[BM * BK], sBh[BM * BK], sBl[BM * BK];
    const int tid = threadIdx.x;
    const int ln  = tid & 63;
    const int wv  = tid >> 6;
    const int bm  = blockIdx.y * BM;
    const int bn  = blockIdx.x * BN;
    const int wm  = (wv >> 1) * 64;
    const int wn  = (wv & 1) * 64;

    f32x4 acc[4][4] = {};

    const int nK = K >> 5;   // K-steps of 32
    for (int kt = 0; kt < nK; ++kt) {
        const int ko = kt * BK;
        __syncthreads();
#pragma unroll
        for (int rnd = 0; rnd < 2; ++rnd) {
            int c   = rnd * 256 + wv * 64 + ln;
            int row = c & 127;
            int kg  = c >> 7;
            int ldsOff = (rnd * 256 + wv * 64) * 8;  // wave-uniform base (u16 elems)
            int ar = bm + row; if (ar >= M) ar = M - 1;
            size_t aOff = (size_t)ar * K + ko + kg * 8;
            gload_lds16(Ah + aOff, sAh + ldsOff);
            gload_lds16(Al + aOff, sAl + ldsOff);
            size_t bOff = (size_t)(bn + row) * K + ko + kg * 8;
            gload_lds16(Bh + bOff, sBh + ldsOff);
            gload_lds16(Bl + bOff, sBl + ldsOff);
        }
        __syncthreads();

        const int kg = ln >> 4;
        const int lr = ln & 15;
        bf16x8 bhf[4], blf[4];
#pragma unroll
        for (int ni = 0; ni < 4; ++ni) {
            int off = kg * (128 * 8) + (wn + ni * 16 + lr) * 8;
            bhf[ni] = *reinterpret_cast<const bf16x8*>(sBh + off);
            blf[ni] = *reinterpret_cast<const bf16x8*>(sBl + off);
        }
#pragma unroll
        for (int mi = 0; mi < 4; ++mi) {
            int off = kg * (128 * 8) + (wm + mi * 16 + lr) * 8;
            bf16x8 ah = *reinterpret_cast<const bf16x8*>(sAh + off);
            bf16x8 al = *reinterpret_cast<const bf16x8*>(sAl + off);
#pragma unroll
            for (int ni = 0; ni < 4; ++ni) {
                acc[mi][ni] = __builtin_amdgcn_mfma_f32_16x16x32_bf16(ah, bhf[ni], acc[mi][ni], 0, 0, 0);
                acc[mi][ni] = __builtin_amdgcn_mfma_f32_16x16x32_bf16(al, bhf[ni], acc[mi][ni], 0, 0, 0);
                acc[mi][ni] = __builtin_amdgcn_mfma_f32_16x16x32_bf16(ah, blf[ni], acc[mi][ni], 0, 0, 0);
            }
        }
    }

    // C/D layout (m89-verified): col = lane&15, row = (lane>>4)*4 + i
    const int lr = ln & 15;
    const int lg = ln >> 4;
#pragma unroll
    for (int mi = 0; mi < 4; ++mi) {
#pragma unroll
        for (int i = 0; i < 4; ++i) {
            int r = bm + wm + mi * 16 + lg * 4 + i;
            if (r < M) {
#pragma unroll
                for (int ni = 0; ni < 4; ++ni) {
                    C[(size_t)r * HC + bn + wn + ni * 16 + lr] = acc[mi][ni][i];
                }
            }
        }
    }
}

// ---------------- per-(node,head) attention scores: a_src, a_dst ----------------
__global__ __launch_bounds__(256) void scores_kernel(const float* __restrict__ h,
                                                     const float* __restrict__ att_s,
                                                     const float* __restrict__ att_d,
                                                     float* __restrict__ asrc,
                                                     float* __restrict__ adst)
{
    int gid = blockIdx.x * 256 + threadIdx.x;
    int wid = gid >> 6;
    int lane = gid & 63;
    if (wid >= N_NODES * HEADS) return;
    int nd = wid / 3;
    int hd = wid - nd * 3;
    const float* hp = h + (size_t)nd * HC + hd * HID;
    float v0 = hp[lane], v1 = hp[lane + 64];
    float s = v0 * att_s[hd * HID + lane] + v1 * att_s[hd * HID + lane + 64];
    float d = v0 * att_d[hd * HID + lane] + v1 * att_d[hd * HID + lane + 64];
#pragma unroll
    for (int off = 32; off; off >>= 1) {
        s += __shfl_xor(s, off);
        d += __shfl_xor(d, off);
    }
    if (lane == 0) { asrc[wid] = s; adst[wid] = d; }
}

__device__ __forceinline__ float lrelu(float x) { return x > 0.f ? x : 0.2f * x; }

// ---------------- per-node softmax + weighted aggregation (+bias +ReLU) ----------------
// one wave per destination node; LANE-PARALLEL weights: lane j owns edge j (and j+64).
// Phase 2 broadcasts (src, w0..w2) via v_readlane -> scalar base + SGPR weights.
__global__ __launch_bounds__(256) void aggregate_kernel(const float* __restrict__ h,
                                                        const float* __restrict__ asrc,
                                                        const float* __restrict__ adst,
                                                        const int* __restrict__ cnt,
                                                        const int* __restrict__ bucket,
                                                        const float* __restrict__ bias,
                                                        u16* __restrict__ hOut,
                                                        u16* __restrict__ lOut,
                                                        float* __restrict__ fOut)
{
    int wv = threadIdx.x >> 6;
    int lane = threadIdx.x & 63;
    int nd = blockIdx.x * 4 + wv;
    if (nd >= N_NODES) return;
    int deg = cnt[nd];
    if (deg > CAP) deg = CAP;
    const int* eb = bucket + nd * CAP;
    float ad0 = adst[nd * 3 + 0], ad1 = adst[nd * 3 + 1], ad2 = adst[nd * 3 + 2];

    // lane j owns edge j (set A) and edge j+64 (set B, nearly always empty)
    bool vA = lane < deg, vB = lane + 64 < deg;
    int sA = vA ? eb[lane] : 0;
    int sB = vB ? eb[lane + 64] : 0;
    float xA0 = -1e30f, xA1 = -1e30f, xA2 = -1e30f;
    float xB0 = -1e30f, xB1 = -1e30f, xB2 = -1e30f;
    if (vA) {
        const float* ap = asrc + (size_t)sA * 3;
        xA0 = lrelu(ap[0] + ad0); xA1 = lrelu(ap[1] + ad1); xA2 = lrelu(ap[2] + ad2);
    }
    if (vB) {
        const float* ap = asrc + (size_t)sB * 3;
        xB0 = lrelu(ap[0] + ad0); xB1 = lrelu(ap[1] + ad1); xB2 = lrelu(ap[2] + ad2);
    }
    // wave max per head
    float m0 = fmaxf(xA0, xB0), m1 = fmaxf(xA1, xB1), m2 = fmaxf(xA2, xB2);
#pragma unroll
    for (int off = 32; off; off >>= 1) {
        m0 = fmaxf(m0, __shfl_xor(m0, off));
        m1 = fmaxf(m1, __shfl_xor(m1, off));
        m2 = fmaxf(m2, __shfl_xor(m2, off));
    }
    // exp (invalid lanes: exp(-1e30 - m) == 0)
    float eA0 = expf(xA0 - m0), eA1 = expf(xA1 - m1), eA2 = expf(xA2 - m2);
    float eB0 = expf(xB0 - m0), eB1 = expf(xB1 - m1), eB2 = expf(xB2 - m2);
    float t0 = eA0 + eB0, t1 = eA1 + eB1, t2 = eA2 + eB2;
#pragma unroll
    for (int off = 32; off; off >>= 1) {
        t0 += __shfl_xor(t0, off);
        t1 += __shfl_xor(t1, off);
        t2 += __shfl_xor(t2, off);
    }
    float r0 = 1.f / (t0 + 1e-16f);
    float r1 = 1.f / (t1 + 1e-16f);
    float r2 = 1.f / (t2 + 1e-16f);
    // per-lane normalized weights for its edge(s)
    float wA0 = eA0 * r0, wA1 = eA1 * r1, wA2 = eA2 * r2;
    float wB0 = eB0 * r0, wB1 = eB1 * r1, wB2 = eB2 * r2;

    // phase 2: lane owns channels {2lane,2lane+1} per head block
    float a00 = 0.f, a01 = 0.f, a10 = 0.f, a11 = 0.f, a20 = 0.f, a21 = 0.f;
    int d0 = deg < 64 ? deg : 64;
    for (int j = 0; j < d0; ++j) {
        int   s  = __builtin_amdgcn_readlane(sA, j);
        float w0 = rdlane_f(wA0, j);
        float w1 = rdlane_f(wA1, j);
        float w2 = rdlane_f(wA2, j);
        const float* hp = h + (size_t)s * HC;
        float2 h0 = *reinterpret_cast<const float2*>(hp + lane * 2);
        float2 h1 = *reinterpret_cast<const float2*>(hp + 128 + lane * 2);
        float2 h2 = *reinterpret_cast<const float2*>(hp + 256 + lane * 2);
        a00 += h0.x * w0; a01 += h0.y * w0;
        a10 += h1.x * w1; a11 += h1.y * w1;
        a20 += h2.x * w2; a21 += h2.y * w2;
    }
    for (int j = 64; j < deg; ++j) {            // rare spill path (deg > 64)
        int   s  = __builtin_amdgcn_readlane(sB, j - 64);
        float w0 = rdlane_f(wB0, j - 64);
        float w1 = rdlane_f(wB1, j - 64);
        float w2 = rdlane_f(wB2, j - 64);
        const float* hp = h + (size_t)s * HC;
        float2 h0 = *reinterpret_cast<const float2*>(hp + lane * 2);
        float2 h1 = *reinterpret_cast<const float2*>(hp + 128 + lane * 2);
        float2 h2 = *reinterpret_cast<const float2*>(hp + 256 + lane * 2);
        a00 += h0.x * w0; a01 += h0.y * w0;
        a10 += h1.x * w1; a11 += h1.y * w1;
        a20 += h2.x * w2; a21 += h2.y * w2;
    }

    // epilogue: +bias, ReLU, store (fp32 or split-bf16)
    size_t base = (size_t)nd * HC;
    float o[6];
    int   c[3] = { lane * 2, 128 + lane * 2, 256 + lane * 2 };
    o[0] = a00 + bias[c[0]];     o[1] = a01 + bias[c[0] + 1];
    o[2] = a10 + bias[c[1]];     o[3] = a11 + bias[c[1] + 1];
    o[4] = a20 + bias[c[2]];     o[5] = a21 + bias[c[2] + 1];
#pragma unroll
    for (int k = 0; k < 6; ++k) o[k] = o[k] > 0.f ? o[k] : 0.f;   // fused ReLU
    if (fOut) {
#pragma unroll
        for (int k = 0; k < 3; ++k)
            *reinterpret_cast<float2*>(fOut + base + c[k]) = make_float2(o[2 * k], o[2 * k + 1]);
    } else {
#pragma unroll
        for (int k = 0; k < 3; ++k) {
            u16 hx = f2bf(o[2 * k]), hy = f2bf(o[2 * k + 1]);
            ushort2 hv = { hx, hy };
            ushort2 lv = { f2bf(o[2 * k] - bf2f(hx)), f2bf(o[2 * k + 1] - bf2f(hy)) };
            *reinterpret_cast<ushort2*>(hOut + base + c[k]) = hv;
            *reinterpret_cast<ushort2*>(lOut + base + c[k]) = lv;
        }
    }
}

// ---------------- final classifier: out[M,40] = A[M,384] @ W[384,40] + b ----------------
__global__ __launch_bounds__(256) void out_gemm(const float* __restrict__ A,
                                                const float* __restrict__ W,
                                                const float* __restrict__ b,
                                                float* __restrict__ out)
{
    int gid = blockIdx.x * 256 + threadIdx.x;
    int r  = gid / 10;
    int c4 = (gid - r * 10) * 4;
    if (r >= N_NODES) return;
    const float* ar = A + (size_t)r * HC;
    float ax = 0.f, ay = 0.f, az = 0.f, aw = 0.f;
#pragma unroll 2
    for (int k = 0; k < HC; k += 4) {
        float4 a  = *reinterpret_cast<const float4*>(ar + k);
        float4 w0 = *reinterpret_cast<const float4*>(W + (size_t)(k + 0) * NCLS + c4);
        float4 w1 = *reinterpret_cast<const float4*>(W + (size_t)(k + 1) * NCLS + c4);
        float4 w2 = *reinterpret_cast<const float4*>(W + (size_t)(k + 2) * NCLS + c4);
        float4 w3 = *reinterpret_cast<const float4*>(W + (size_t)(k + 3) * NCLS + c4);
        ax += a.x * w0.x + a.y * w1.x + a.z * w2.x + a.w * w3.x;
        ay += a.x * w0.y + a.y * w1.y + a.z * w2.y + a.w * w3.y;
        az += a.x * w0.z + a.y * w1.z + a.z * w2.z + a.w * w3.z;
        aw += a.x * w0.w + a.y * w1.w + a.z * w2.w + a.w * w3.w;
    }
    float4 bb = *reinterpret_cast<const float4*>(b + c4);
    float4 o = make_float4(ax + bb.x, ay + bb.y, az + bb.z, aw + bb.w);
    *reinterpret_cast<float4*>(out + (size_t)r * NCLS + c4) = o;
}

extern "C" void kernel_launch(void* const* d_in, const int* in_sizes, int n_in,
                              void* d_out, int out_size, void* d_ws, size_t ws_size,
                              hipStream_t stream)
{
    const float* x    = (const float*)d_in[0];
    const int*   ei   = (const int*)d_in[1];     // int32 (harness ships integer inputs as int32)
    const float* W1   = (const float*)d_in[2];
    const float* as1  = (const float*)d_in[3];
    const float* ad1  = (const float*)d_in[4];
    const float* b1   = (const float*)d_in[5];
    const float* W2   = (const float*)d_in[6];
    const float* as2  = (const float*)d_in[7];
    const float* ad2  = (const float*)d_in[8];
    const float* b2   = (const float*)d_in[9];
    const float* outW = (const float*)d_in[10];
    const float* outb = (const float*)d_in[11];
    float* out = (float*)d_out;

    // ---- workspace layout ----
    float* bufH = (float*)d_ws;                          // [N,384] fp32 gemm out
    char*  reg2 = (char*)(bufH + (size_t)N_NODES * HC);  // 76.8 MB region, disjoint lifetimes
    u16*   xh   = (u16*)reg2;
    u16*   xl   = xh + (size_t)N_NODES * IN_DIM;
    u16*   aggH = (u16*)reg2;
    u16*   aggL = aggH + (size_t)N_NODES * HC;
    float* bufA = (float*)reg2;
    char*  tail = reg2 + (size_t)N_NODES * HC * 4;
    u16* W1tH = (u16*)tail;                              // [384][256]
    u16* W1tL = W1tH + (size_t)IN_DIM * HC;
    u16* W2tH = W1tL + (size_t)IN_DIM * HC;              // [384][384]
    u16* W2tL = W2tH + (size_t)HC * HC;
    float* asrc = (float*)(W2tL + (size_t)HC * HC);
    float* adst = asrc + (size_t)N_NODES * HEADS;
    int*   cnt    = (int*)(adst + (size_t)N_NODES * HEADS);
    int*   bucket = cnt + N_NODES;

    hipMemsetAsync(cnt, 0, N_NODES * sizeof(int), stream);
    count_scatter<<<(ET + 255) / 256, 256, 0, stream>>>(ei, cnt, bucket);

    split_kernel<<<(N_NODES * IN_DIM / 4 + 255) / 256, 256, 0, stream>>>(x, xh, xl, N_NODES * IN_DIM / 4);
    split_wt<<<(IN_DIM * HC + 255) / 256, 256, 0, stream>>>(W1, W1tH, W1tL, IN_DIM);
    split_wt<<<(HC * HC + 255) / 256, 256, 0, stream>>>(W2, W2tH, W2tL, HC);

    dim3 gg(HC / BN, (N_NODES + BM - 1) / BM);   // (3, 391)
    // ---- layer 1 ----
    gemm_mfma<<<gg, 256, 0, stream>>>(xh, xl, W1tH, W1tL, bufH, N_NODES, IN_DIM);
    scores_kernel<<<(N_NODES * HEADS + 3) / 4, 256, 0, stream>>>(bufH, as1, ad1, asrc, adst);
    aggregate_kernel<<<(N_NODES + 3) / 4, 256, 0, stream>>>(bufH, asrc, adst, cnt, bucket, b1,
                                                            aggH, aggL, nullptr);
    // ---- layer 2 ----
    gemm_mfma<<<gg, 256, 0, stream>>>(aggH, aggL, W2tH, W2tL, bufH, N_NODES, HC);
    scores_kernel<<<(N_NODES * HEADS + 3) / 4, 256, 0, stream>>>(bufH, as2, ad2, asrc, adst);
    aggregate_kernel<<<(N_NODES + 3) / 4, 256, 0, stream>>>(bufH, asrc, adst, cnt, bucket, b2,
                                                            nullptr, nullptr, bufA);
    // ---- classifier ----
    out_gemm<<<(N_NODES * 10 + 255) / 256, 256, 0, stream>>>(bufA, outW, outb, out);
}

// Round 6
// 862.351 us; speedup vs baseline: 1.3839x; 1.0207x over previous
//
#include <hip/hip_runtime.h>
#include <cstdint>
#include <cstddef>

typedef unsigned short u16;
typedef unsigned int   u32;
typedef __attribute__((ext_vector_type(8))) short bf16x8;
typedef __attribute__((ext_vector_type(4))) float f32x4;

#define N_NODES 50000
#define N_EDGES 800000
#define ET (N_EDGES + N_NODES)   // edges + self loops = 850000
#define IN_DIM 256
#define HID 128
#define HEADS 3
#define HC 384                   // HEADS * HID
#define NCLS 40
#define CAP 96                   // per-node in-edge bucket capacity (deg ~ Poisson(17), max@50K nodes ~45)

// ---------------- bf16 helpers (RNE) ----------------
__device__ __forceinline__ u16 f2bf(float f) {
    union { float f; u32 u; } x; x.f = f;
    u32 r = x.u + 0x7fffu + ((x.u >> 16) & 1u);
    return (u16)(r >> 16);
}
__device__ __forceinline__ float bf2f(u16 b) {
    union { u32 u; float f; } x; x.u = ((u32)b) << 16; return x.f;
}

__device__ __forceinline__ void gload_lds16(const void* g, void* l) {
    __builtin_amdgcn_global_load_lds((const __attribute__((address_space(1))) void*)g,
                                     (__attribute__((address_space(3))) void*)l, 16, 0, 0);
}

__device__ __forceinline__ float rdlane_f(float v, int l) {
    return __int_as_float(__builtin_amdgcn_readlane(__float_as_int(v), l));
}

// ---------------- CSR-by-destination build (bucketed, no sort/scan) ----------------
__global__ __launch_bounds__(256) void count_scatter(const int* __restrict__ ei,
                                                     int* __restrict__ cnt,
                                                     int* __restrict__ bucket)
{
    int e = blockIdx.x * 256 + threadIdx.x;
    if (e >= ET) return;
    int s, d;
    if (e < N_EDGES) { s = ei[e]; d = ei[N_EDGES + e]; }
    else             { s = e - N_EDGES; d = s; }          // self loop
    int pos = atomicAdd(&cnt[d], 1);
    if (pos < CAP) bucket[d * CAP + pos] = s;
}

// ---------------- fp32 -> (hi,lo) bf16 split, flat, 4 elems/thread ----------------
__global__ __launch_bounds__(256) void split_kernel(const float* __restrict__ in,
                                                    u16* __restrict__ hi,
                                                    u16* __restrict__ lo, int n4)
{
    int i = blockIdx.x * 256 + threadIdx.x;
    if (i >= n4) return;
    float4 v = reinterpret_cast<const float4*>(in)[i];
    ushort4 h, l;
    h.x = f2bf(v.x); l.x = f2bf(v.x - bf2f(h.x));
    h.y = f2bf(v.y); l.y = f2bf(v.y - bf2f(h.y));
    h.z = f2bf(v.z); l.z = f2bf(v.z - bf2f(h.z));
    h.w = f2bf(v.w); l.w = f2bf(v.w - bf2f(h.w));
    reinterpret_cast<ushort4*>(hi)[i] = h;
    reinterpret_cast<ushort4*>(lo)[i] = l;
}

// ---------------- W[K][N] -> fragment-order split Wt{h,l}[K/8][HC][8] ----------------
// A wave's B-fragment load (16 consecutive cols x 8 k) is then 256 B contiguous.
__global__ __launch_bounds__(256) void split_wt(const float* __restrict__ W,
                                                u16* __restrict__ WtH,
                                                u16* __restrict__ WtL, int K)
{
    int idx = blockIdx.x * 256 + threadIdx.x;
    if (idx >= K * HC) return;
    int k = idx / HC, n = idx - k * HC;
    float v = W[idx];
    u16 h = f2bf(v);
    size_t o = ((size_t)(k >> 3) * HC + n) * 8 + (k & 7);
    WtH[o] = h;
    WtL[o] = f2bf(v - bf2f(h));
}

// ---------------- split-bf16 MFMA GEMM: C[M,HC] = A[M,K] @ W^T ----------------
// A: double-buffered LDS (global_load_lds, [kgrp][row][8] layout).
// B: direct global->reg fragment loads from [K/8][HC][8] (L2-resident weights).
// Per K-step: barrier -> B-frag loads -> stage A(next) -> ds_read A(cur) -> 48 MFMA.
// Loop unrolled x2 with statically distinct LDS buffers (clean alias analysis).
#define BM 128
#define BN 128
#define BK 32
__global__ __launch_bounds__(256) void gemm_mfma(const u16* __restrict__ Ah, const u16* __restrict__ Al,
                                                 const u16* __restrict__ Bh, const u16* __restrict__ Bl,
                                                 float* __restrict__ C, int M, int K)
{
    __shared__ u16 sAh0[BM * BK], sAl0[BM * BK], sAh1[BM * BK], sAl1[BM * BK];
    const int tid = threadIdx.x;
    const int ln  = tid & 63;
    const int wv  = tid >> 6;
    const int bm  = blockIdx.y * BM;
    const int bn  = blockIdx.x * BN;
    const int wm  = (wv >> 1) * 64;
    const int wn  = (wv & 1) * 64;
    const int kg  = ln >> 4;
    const int lr  = ln & 15;
    const int nK  = K >> 5;     // K-steps of 32 (8 or 12, always even)

    f32x4 acc[4][4] = {};

    // stage A-tile (ko) into given buffers; LDS dest wave-uniform + lane*16 (linear)
    auto stage = [&](u16* dAh, u16* dAl, int ko) {
#pragma unroll
        for (int rnd = 0; rnd < 2; ++rnd) {
            int c   = rnd * 256 + wv * 64 + ln;     // chunk id 0..511
            int row = c & 127;
            int kgp = c >> 7;
            int ldsOff = (rnd * 256 + wv * 64) * 8; // wave-uniform (elements)
            int ar = bm + row; if (ar >= M) ar = M - 1;
            size_t off = (size_t)ar * K + ko + kgp * 8;
            gload_lds16(Ah + off, dAh + ldsOff);
            gload_lds16(Al + off, dAl + ldsOff);
        }
    };

    // one K-step: read curA, prefetch nxtA for kt+1 (if pref)
    auto step = [&](const u16* curAh, const u16* curAl, u16* nxtAh, u16* nxtAl,
                    int kt, bool pref) {
        const int ko = kt * BK;
        bf16x8 bhf[4], blf[4];
        size_t bb = ((size_t)((ko >> 3) + kg) * HC + bn + wn + lr) * 8;
#pragma unroll
        for (int ni = 0; ni < 4; ++ni) {
            bhf[ni] = *reinterpret_cast<const bf16x8*>(Bh + bb + ni * 128);
            blf[ni] = *reinterpret_cast<const bf16x8*>(Bl + bb + ni * 128);
        }
        if (pref) stage(nxtAh, nxtAl, ko + BK);     // issued after B: vmcnt(4) leaves it in flight
#pragma unroll
        for (int mi = 0; mi < 4; ++mi) {
            int off = (kg * 128 + wm + mi * 16 + lr) * 8;
            bf16x8 ah = *reinterpret_cast<const bf16x8*>(curAh + off);
            bf16x8 al = *reinterpret_cast<const bf16x8*>(curAl + off);
#pragma unroll
            for (int ni = 0; ni < 4; ++ni) {
                acc[mi][ni] = __builtin_amdgcn_mfma_f32_16x16x32_bf16(ah, bhf[ni], acc[mi][ni], 0, 0, 0);
                acc[mi][ni] = __builtin_amdgcn_mfma_f32_16x16x32_bf16(al, bhf[ni], acc[mi][ni], 0, 0, 0);
                acc[mi][ni] = __builtin_amdgcn_mfma_f32_16x16x32_bf16(ah, blf[ni], acc[mi][ni], 0, 0, 0);
            }
        }
    };

    stage(sAh0, sAl0, 0);
    for (int kt = 0; kt < nK; kt += 2) {
        __syncthreads();                                  // drains stage into buf0
        step(sAh0, sAl0, sAh1, sAl1, kt, true);           // kt+1 < nK always (nK even)
        __syncthreads();                                  // drains stage into buf1
        step(sAh1, sAl1, sAh0, sAl0, kt + 1, kt + 2 < nK);
    }

    // C/D layout (m89-verified): col = lane&15, row = (lane>>4)*4 + i
#pragma unroll
    for (int mi = 0; mi < 4; ++mi) {
#pragma unroll
        for (int i = 0; i < 4; ++i) {
            int r = bm + wm + mi * 16 + kg * 4 + i;
            if (r < M) {
#pragma unroll
                for (int ni = 0; ni < 4; ++ni) {
                    C[(size_t)r * HC + bn + wn + ni * 16 + lr] = acc[mi][ni][i];
                }
            }
        }
    }
}

// ---------------- per-(node,head) attention scores: a_src, a_dst ----------------
__global__ __launch_bounds__(256) void scores_kernel(const float* __restrict__ h,
                                                     const float* __restrict__ att_s,
                                                     const float* __restrict__ att_d,
                                                     float* __restrict__ asrc,
                                                     float* __restrict__ adst)
{
    int gid = blockIdx.x * 256 + threadIdx.x;
    int wid = gid >> 6;
    int lane = gid & 63;
    if (wid >= N_NODES * HEADS) return;
    int nd = wid / 3;
    int hd = wid - nd * 3;
    const float* hp = h + (size_t)nd * HC + hd * HID;
    float v0 = hp[lane], v1 = hp[lane + 64];
    float s = v0 * att_s[hd * HID + lane] + v1 * att_s[hd * HID + lane + 64];
    float d = v0 * att_d[hd * HID + lane] + v1 * att_d[hd * HID + lane + 64];
#pragma unroll
    for (int off = 32; off; off >>= 1) {
        s += __shfl_xor(s, off);
        d += __shfl_xor(d, off);
    }
    if (lane == 0) { asrc[wid] = s; adst[wid] = d; }
}

__device__ __forceinline__ float lrelu(float x) { return x > 0.f ? x : 0.2f * x; }

// ---------------- per-node softmax + weighted aggregation (+bias +ReLU) ----------------
// one wave per destination node; lane-parallel weights, readlane broadcast in phase 2
__global__ __launch_bounds__(256) void aggregate_kernel(const float* __restrict__ h,
                                                        const float* __restrict__ asrc,
                                                        const float* __restrict__ adst,
                                                        const int* __restrict__ cnt,
                                                        const int* __restrict__ bucket,
                                                        const float* __restrict__ bias,
                                                        u16* __restrict__ hOut,
                                                        u16* __restrict__ lOut,
                                                        float* __restrict__ fOut)
{
    int wv = threadIdx.x >> 6;
    int lane = threadIdx.x & 63;
    int nd = blockIdx.x * 4 + wv;
    if (nd >= N_NODES) return;
    int deg = cnt[nd];
    if (deg > CAP) deg = CAP;
    const int* eb = bucket + nd * CAP;
    float ad0 = adst[nd * 3 + 0], ad1 = adst[nd * 3 + 1], ad2 = adst[nd * 3 + 2];

    bool vA = lane < deg, vB = lane + 64 < deg;
    int sA = vA ? eb[lane] : 0;
    int sB = vB ? eb[lane + 64] : 0;
    float xA0 = -1e30f, xA1 = -1e30f, xA2 = -1e30f;
    float xB0 = -1e30f, xB1 = -1e30f, xB2 = -1e30f;
    if (vA) {
        const float* ap = asrc + (size_t)sA * 3;
        xA0 = lrelu(ap[0] + ad0); xA1 = lrelu(ap[1] + ad1); xA2 = lrelu(ap[2] + ad2);
    }
    if (vB) {
        const float* ap = asrc + (size_t)sB * 3;
        xB0 = lrelu(ap[0] + ad0); xB1 = lrelu(ap[1] + ad1); xB2 = lrelu(ap[2] + ad2);
    }
    float m0 = fmaxf(xA0, xB0), m1 = fmaxf(xA1, xB1), m2 = fmaxf(xA2, xB2);
#pragma unroll
    for (int off = 32; off; off >>= 1) {
        m0 = fmaxf(m0, __shfl_xor(m0, off));
        m1 = fmaxf(m1, __shfl_xor(m1, off));
        m2 = fmaxf(m2, __shfl_xor(m2, off));
    }
    float eA0 = expf(xA0 - m0), eA1 = expf(xA1 - m1), eA2 = expf(xA2 - m2);
    float eB0 = expf(xB0 - m0), eB1 = expf(xB1 - m1), eB2 = expf(xB2 - m2);
    float t0 = eA0 + eB0, t1 = eA1 + eB1, t2 = eA2 + eB2;
#pragma unroll
    for (int off = 32; off; off >>= 1) {
        t0 += __shfl_xor(t0, off);
        t1 += __shfl_xor(t1, off);
        t2 += __shfl_xor(t2, off);
    }
    float r0 = 1.f / (t0 + 1e-16f);
    float r1 = 1.f / (t1 + 1e-16f);
    float r2 = 1.f / (t2 + 1e-16f);
    float wA0 = eA0 * r0, wA1 = eA1 * r1, wA2 = eA2 * r2;
    float wB0 = eB0 * r0, wB1 = eB1 * r1, wB2 = eB2 * r2;

    float a00 = 0.f, a01 = 0.f, a10 = 0.f, a11 = 0.f, a20 = 0.f, a21 = 0.f;
    int d0 = deg < 64 ? deg : 64;
    for (int j = 0; j < d0; ++j) {
        int   s  = __builtin_amdgcn_readlane(sA, j);
        float w0 = rdlane_f(wA0, j);
        float w1 = rdlane_f(wA1, j);
        float w2 = rdlane_f(wA2, j);
        const float* hp = h + (size_t)s * HC;
        float2 h0 = *reinterpret_cast<const float2*>(hp + lane * 2);
        float2 h1 = *reinterpret_cast<const float2*>(hp + 128 + lane * 2);
        float2 h2 = *reinterpret_cast<const float2*>(hp + 256 + lane * 2);
        a00 += h0.x * w0; a01 += h0.y * w0;
        a10 += h1.x * w1; a11 += h1.y * w1;
        a20 += h2.x * w2; a21 += h2.y * w2;
    }
    for (int j = 64; j < deg; ++j) {            // rare spill path (deg > 64)
        int   s  = __builtin_amdgcn_readlane(sB, j - 64);
        float w0 = rdlane_f(wB0, j - 64);
        float w1 = rdlane_f(wB1, j - 64);
        float w2 = rdlane_f(wB2, j - 64);
        const float* hp = h + (size_t)s * HC;
        float2 h0 = *reinterpret_cast<const float2*>(hp + lane * 2);
        float2 h1 = *reinterpret_cast<const float2*>(hp + 128 + lane * 2);
        float2 h2 = *reinterpret_cast<const float2*>(hp + 256 + lane * 2);
        a00 += h0.x * w0; a01 += h0.y * w0;
        a10 += h1.x * w1; a11 += h1.y * w1;
        a20 += h2.x * w2; a21 += h2.y * w2;
    }

    size_t base = (size_t)nd * HC;
    float o[6];
    int   c[3] = { lane * 2, 128 + lane * 2, 256 + lane * 2 };
    o[0] = a00 + bias[c[0]];     o[1] = a01 + bias[c[0] + 1];
    o[2] = a10 + bias[c[1]];     o[3] = a11 + bias[c[1] + 1];
    o[4] = a20 + bias[c[2]];     o[5] = a21 + bias[c[2] + 1];
#pragma unroll
    for (int k = 0; k < 6; ++k) o[k] = o[k] > 0.f ? o[k] : 0.f;   // fused ReLU
    if (fOut) {
#pragma unroll
        for (int k = 0; k < 3; ++k)
            *reinterpret_cast<float2*>(fOut + base + c[k]) = make_float2(o[2 * k], o[2 * k + 1]);
    } else {
#pragma unroll
        for (int k = 0; k < 3; ++k) {
            u16 hx = f2bf(o[2 * k]), hy = f2bf(o[2 * k + 1]);
            ushort2 hv = { hx, hy };
            ushort2 lv = { f2bf(o[2 * k] - bf2f(hx)), f2bf(o[2 * k + 1] - bf2f(hy)) };
            *reinterpret_cast<ushort2*>(hOut + base + c[k]) = hv;
            *reinterpret_cast<ushort2*>(lOut + base + c[k]) = lv;
        }
    }
}

// ---------------- final classifier: out[M,40] = A[M,384] @ W[384,40] + b ----------------
__global__ __launch_bounds__(256) void out_gemm(const float* __restrict__ A,
                                                const float* __restrict__ W,
                                                const float* __restrict__ b,
                                                float* __restrict__ out)
{
    int gid = blockIdx.x * 256 + threadIdx.x;
    int r  = gid / 10;
    int c4 = (gid - r * 10) * 4;
    if (r >= N_NODES) return;
    const float* ar = A + (size_t)r * HC;
    float ax = 0.f, ay = 0.f, az = 0.f, aw = 0.f;
#pragma unroll 2
    for (int k = 0; k < HC; k += 4) {
        float4 a  = *reinterpret_cast<const float4*>(ar + k);
        float4 w0 = *reinterpret_cast<const float4*>(W + (size_t)(k + 0) * NCLS + c4);
        float4 w1 = *reinterpret_cast<const float4*>(W + (size_t)(k + 1) * NCLS + c4);
        float4 w2 = *reinterpret_cast<const float4*>(W + (size_t)(k + 2) * NCLS + c4);
        float4 w3 = *reinterpret_cast<const float4*>(W + (size_t)(k + 3) * NCLS + c4);
        ax += a.x * w0.x + a.y * w1.x + a.z * w2.x + a.w * w3.x;
        ay += a.x * w0.y + a.y * w1.y + a.z * w2.y + a.w * w3.y;
        az += a.x * w0.z + a.y * w1.z + a.z * w2.z + a.w * w3.z;
        aw += a.x * w0.w + a.y * w1.w + a.z * w2.w + a.w * w3.w;
    }
    float4 bb = *reinterpret_cast<const float4*>(b + c4);
    float4 o = make_float4(ax + bb.x, ay + bb.y, az + bb.z, aw + bb.w);
    *reinterpret_cast<float4*>(out + (size_t)r * NCLS + c4) = o;
}

extern "C" void kernel_launch(void* const* d_in, const int* in_sizes, int n_in,
                              void* d_out, int out_size, void* d_ws, size_t ws_size,
                              hipStream_t stream)
{
    const float* x    = (const float*)d_in[0];
    const int*   ei   = (const int*)d_in[1];     // int32 (harness ships integer inputs as int32)
    const float* W1   = (const float*)d_in[2];
    const float* as1  = (const float*)d_in[3];
    const float* ad1  = (const float*)d_in[4];
    const float* b1   = (const float*)d_in[5];
    const float* W2   = (const float*)d_in[6];
    const float* as2  = (const float*)d_in[7];
    const float* ad2  = (const float*)d_in[8];
    const float* b2   = (const float*)d_in[9];
    const float* outW = (const float*)d_in[10];
    const float* outb = (const float*)d_in[11];
    float* out = (float*)d_out;

    // ---- workspace layout ----
    float* bufH = (float*)d_ws;                          // [N,384] fp32 gemm out
    char*  reg2 = (char*)(bufH + (size_t)N_NODES * HC);  // 76.8 MB region, disjoint lifetimes
    u16*   xh   = (u16*)reg2;
    u16*   xl   = xh + (size_t)N_NODES * IN_DIM;
    u16*   aggH = (u16*)reg2;
    u16*   aggL = aggH + (size_t)N_NODES * HC;
    float* bufA = (float*)reg2;
    char*  tail = reg2 + (size_t)N_NODES * HC * 4;
    u16* W1tH = (u16*)tail;                              // [256/8][384][8]
    u16* W1tL = W1tH + (size_t)IN_DIM * HC;
    u16* W2tH = W1tL + (size_t)IN_DIM * HC;              // [384/8][384][8]
    u16* W2tL = W2tH + (size_t)HC * HC;
    float* asrc = (float*)(W2tL + (size_t)HC * HC);
    float* adst = asrc + (size_t)N_NODES * HEADS;
    int*   cnt    = (int*)(adst + (size_t)N_NODES * HEADS);
    int*   bucket = cnt + N_NODES;

    hipMemsetAsync(cnt, 0, N_NODES * sizeof(int), stream);
    count_scatter<<<(ET + 255) / 256, 256, 0, stream>>>(ei, cnt, bucket);

    split_kernel<<<(N_NODES * IN_DIM / 4 + 255) / 256, 256, 0, stream>>>(x, xh, xl, N_NODES * IN_DIM / 4);
    split_wt<<<(IN_DIM * HC + 255) / 256, 256, 0, stream>>>(W1, W1tH, W1tL, IN_DIM);
    split_wt<<<(HC * HC + 255) / 256, 256, 0, stream>>>(W2, W2tH, W2tL, HC);

    dim3 gg(HC / BN, (N_NODES + BM - 1) / BM);   // (3, 391)
    // ---- layer 1 ----
    gemm_mfma<<<gg, 256, 0, stream>>>(xh, xl, W1tH, W1tL, bufH, N_NODES, IN_DIM);
    scores_kernel<<<(N_NODES * HEADS + 3) / 4, 256, 0, stream>>>(bufH, as1, ad1, asrc, adst);
    aggregate_kernel<<<(N_NODES + 3) / 4, 256, 0, stream>>>(bufH, asrc, adst, cnt, bucket, b1,
                                                            aggH, aggL, nullptr);
    // ---- layer 2 ----
    gemm_mfma<<<gg, 256, 0, stream>>>(aggH, aggL, W2tH, W2tL, bufH, N_NODES, HC);
    scores_kernel<<<(N_NODES * HEADS + 3) / 4, 256, 0, stream>>>(bufH, as2, ad2, asrc, adst);
    aggregate_kernel<<<(N_NODES + 3) / 4, 256, 0, stream>>>(bufH, asrc, adst, cnt, bucket, b2,
                                                            nullptr, nullptr, bufA);
    // ---- classifier ----
    out_gemm<<<(N_NODES * 10 + 255) / 256, 256, 0, stream>>>(bufA, outW, outb, out);
}

// Round 7
// 680.354 us; speedup vs baseline: 1.7541x; 1.2675x over previous
//
#include <hip/hip_runtime.h>
#include <cstdint>
#include <cstddef>

typedef unsigned short u16;
typedef unsigned int   u32;
typedef __attribute__((ext_vector_type(8))) short bf16x8;
typedef __attribute__((ext_vector_type(4))) float f32x4;

#define N_NODES 50000
#define N_EDGES 800000
#define ET (N_EDGES + N_NODES)   // edges + self loops = 850000
#define IN_DIM 256
#define HID 128
#define HEADS 3
#define HC 384                   // HEADS * HID
#define NCLS 40
#define CAP 96                   // per-node in-edge bucket capacity (deg ~ Poisson(17), max@50K nodes ~45)

// ---------------- bf16 helpers (RNE) ----------------
__device__ __forceinline__ u16 f2bf(float f) {
    union { float f; u32 u; } x; x.f = f;
    u32 r = x.u + 0x7fffu + ((x.u >> 16) & 1u);
    return (u16)(r >> 16);
}
__device__ __forceinline__ float bf2f(u16 b) {
    union { u32 u; float f; } x; x.u = ((u32)b) << 16; return x.f;
}

__device__ __forceinline__ void gload_lds16(const void* g, void* l) {
    __builtin_amdgcn_global_load_lds((const __attribute__((address_space(1))) void*)g,
                                     (__attribute__((address_space(3))) void*)l, 16, 0, 0);
}

__device__ __forceinline__ float rdlane_f(float v, int l) {
    return __int_as_float(__builtin_amdgcn_readlane(__float_as_int(v), l));
}

// ---------------- CSR-by-destination build (bucketed, no sort/scan) ----------------
__global__ __launch_bounds__(256) void count_scatter(const int* __restrict__ ei,
                                                     int* __restrict__ cnt,
                                                     int* __restrict__ bucket)
{
    int e = blockIdx.x * 256 + threadIdx.x;
    if (e >= ET) return;
    int s, d;
    if (e < N_EDGES) { s = ei[e]; d = ei[N_EDGES + e]; }
    else             { s = e - N_EDGES; d = s; }          // self loop
    int pos = atomicAdd(&cnt[d], 1);
    if (pos < CAP) bucket[d * CAP + pos] = s;
}

// ---------------- fp32 -> (hi,lo) bf16 split, flat, 4 elems/thread ----------------
__global__ __launch_bounds__(256) void split_kernel(const float* __restrict__ in,
                                                    u16* __restrict__ hi,
                                                    u16* __restrict__ lo, int n4)
{
    int i = blockIdx.x * 256 + threadIdx.x;
    if (i >= n4) return;
    float4 v = reinterpret_cast<const float4*>(in)[i];
    ushort4 h, l;
    h.x = f2bf(v.x); l.x = f2bf(v.x - bf2f(h.x));
    h.y = f2bf(v.y); l.y = f2bf(v.y - bf2f(h.y));
    h.z = f2bf(v.z); l.z = f2bf(v.z - bf2f(h.z));
    h.w = f2bf(v.w); l.w = f2bf(v.w - bf2f(h.w));
    reinterpret_cast<ushort4*>(hi)[i] = h;
    reinterpret_cast<ushort4*>(lo)[i] = l;
}

// ---------------- W[K][N] -> fragment-order split Wt{h,l}[K/8][HC][8] ----------------
__global__ __launch_bounds__(256) void split_wt(const float* __restrict__ W,
                                                u16* __restrict__ WtH,
                                                u16* __restrict__ WtL, int K)
{
    int idx = blockIdx.x * 256 + threadIdx.x;
    if (idx >= K * HC) return;
    int k = idx / HC, n = idx - k * HC;
    float v = W[idx];
    u16 h = f2bf(v);
    size_t o = ((size_t)(k >> 3) * HC + n) * 8 + (k & 7);
    WtH[o] = h;
    WtL[o] = f2bf(v - bf2f(h));
}

// ---------------- split-bf16 MFMA GEMM: Cb[M,HC] = bf16(A[M,K] @ W^T) ----------------
// A: double-buffered LDS (global_load_lds, [kgrp][row][8] layout).
// B: direct global->reg fragment loads from [K/8][HC][8] (L2-resident weights).
#define BM 128
#define BN 128
#define BK 32
__global__ __launch_bounds__(256) void gemm_mfma(const u16* __restrict__ Ah, const u16* __restrict__ Al,
                                                 const u16* __restrict__ Bh, const u16* __restrict__ Bl,
                                                 u16* __restrict__ Cb, int M, int K)
{
    __shared__ u16 sAh0[BM * BK], sAl0[BM * BK], sAh1[BM * BK], sAl1[BM * BK];
    const int tid = threadIdx.x;
    const int ln  = tid & 63;
    const int wv  = tid >> 6;
    const int bm  = blockIdx.y * BM;
    const int bn  = blockIdx.x * BN;
    const int wm  = (wv >> 1) * 64;
    const int wn  = (wv & 1) * 64;
    const int kg  = ln >> 4;
    const int lr  = ln & 15;
    const int nK  = K >> 5;     // K-steps of 32 (8 or 12, always even)

    f32x4 acc[4][4] = {};

    auto stage = [&](u16* dAh, u16* dAl, int ko) {
#pragma unroll
        for (int rnd = 0; rnd < 2; ++rnd) {
            int c   = rnd * 256 + wv * 64 + ln;     // chunk id 0..511
            int row = c & 127;
            int kgp = c >> 7;
            int ldsOff = (rnd * 256 + wv * 64) * 8; // wave-uniform (elements)
            int ar = bm + row; if (ar >= M) ar = M - 1;
            size_t off = (size_t)ar * K + ko + kgp * 8;
            gload_lds16(Ah + off, dAh + ldsOff);
            gload_lds16(Al + off, dAl + ldsOff);
        }
    };

    auto step = [&](const u16* curAh, const u16* curAl, u16* nxtAh, u16* nxtAl,
                    int kt, bool pref) {
        const int ko = kt * BK;
        bf16x8 bhf[4], blf[4];
        size_t bb = ((size_t)((ko >> 3) + kg) * HC + bn + wn + lr) * 8;
#pragma unroll
        for (int ni = 0; ni < 4; ++ni) {
            bhf[ni] = *reinterpret_cast<const bf16x8*>(Bh + bb + ni * 128);
            blf[ni] = *reinterpret_cast<const bf16x8*>(Bl + bb + ni * 128);
        }
        if (pref) stage(nxtAh, nxtAl, ko + BK);
#pragma unroll
        for (int mi = 0; mi < 4; ++mi) {
            int off = (kg * 128 + wm + mi * 16 + lr) * 8;
            bf16x8 ah = *reinterpret_cast<const bf16x8*>(curAh + off);
            bf16x8 al = *reinterpret_cast<const bf16x8*>(curAl + off);
#pragma unroll
            for (int ni = 0; ni < 4; ++ni) {
                acc[mi][ni] = __builtin_amdgcn_mfma_f32_16x16x32_bf16(ah, bhf[ni], acc[mi][ni], 0, 0, 0);
                acc[mi][ni] = __builtin_amdgcn_mfma_f32_16x16x32_bf16(al, bhf[ni], acc[mi][ni], 0, 0, 0);
                acc[mi][ni] = __builtin_amdgcn_mfma_f32_16x16x32_bf16(ah, blf[ni], acc[mi][ni], 0, 0, 0);
            }
        }
    };

    stage(sAh0, sAl0, 0);
    for (int kt = 0; kt < nK; kt += 2) {
        __syncthreads();
        step(sAh0, sAl0, sAh1, sAl1, kt, true);
        __syncthreads();
        step(sAh1, sAl1, sAh0, sAl0, kt + 1, kt + 2 < nK);
    }

    // C/D layout (m89-verified): col = lane&15, row = (lane>>4)*4 + i; store bf16
#pragma unroll
    for (int mi = 0; mi < 4; ++mi) {
#pragma unroll
        for (int i = 0; i < 4; ++i) {
            int r = bm + wm + mi * 16 + kg * 4 + i;
            if (r < M) {
#pragma unroll
                for (int ni = 0; ni < 4; ++ni) {
                    Cb[(size_t)r * HC + bn + wn + ni * 16 + lr] = f2bf(acc[mi][ni][i]);
                }
            }
        }
    }
}

// ---------------- per-(node,head) attention scores from bf16 h ----------------
__global__ __launch_bounds__(256) void scores_kernel(const u16* __restrict__ h,
                                                     const float* __restrict__ att_s,
                                                     const float* __restrict__ att_d,
                                                     float* __restrict__ asrc,
                                                     float* __restrict__ adst)
{
    int gid = blockIdx.x * 256 + threadIdx.x;
    int wid = gid >> 6;
    int lane = gid & 63;
    if (wid >= N_NODES * HEADS) return;
    int nd = wid / 3;
    int hd = wid - nd * 3;
    const u16* hp = h + (size_t)nd * HC + hd * HID;
    float v0 = bf2f(hp[lane]), v1 = bf2f(hp[lane + 64]);
    float s = v0 * att_s[hd * HID + lane] + v1 * att_s[hd * HID + lane + 64];
    float d = v0 * att_d[hd * HID + lane] + v1 * att_d[hd * HID + lane + 64];
#pragma unroll
    for (int off = 32; off; off >>= 1) {
        s += __shfl_xor(s, off);
        d += __shfl_xor(d, off);
    }
    if (lane == 0) { asrc[wid] = s; adst[wid] = d; }
}

__device__ __forceinline__ float lrelu(float x) { return x > 0.f ? x : 0.2f * x; }

// ---------------- per-node softmax + weighted aggregation (+bias +ReLU) ----------------
// one wave per destination node; lane-parallel weights, readlane broadcast in phase 2.
// h gathered as bf16 (768 B/edge instead of 1536 B) — halves the dominant traffic.
__global__ __launch_bounds__(256) void aggregate_kernel(const u16* __restrict__ h,
                                                        const float* __restrict__ asrc,
                                                        const float* __restrict__ adst,
                                                        const int* __restrict__ cnt,
                                                        const int* __restrict__ bucket,
                                                        const float* __restrict__ bias,
                                                        u16* __restrict__ hOut,
                                                        u16* __restrict__ lOut,
                                                        float* __restrict__ fOut)
{
    int wv = threadIdx.x >> 6;
    int lane = threadIdx.x & 63;
    int nd = blockIdx.x * 4 + wv;
    if (nd >= N_NODES) return;
    int deg = cnt[nd];
    if (deg > CAP) deg = CAP;
    const int* eb = bucket + nd * CAP;
    float ad0 = adst[nd * 3 + 0], ad1 = adst[nd * 3 + 1], ad2 = adst[nd * 3 + 2];

    bool vA = lane < deg, vB = lane + 64 < deg;
    int sA = vA ? eb[lane] : 0;
    int sB = vB ? eb[lane + 64] : 0;
    float xA0 = -1e30f, xA1 = -1e30f, xA2 = -1e30f;
    float xB0 = -1e30f, xB1 = -1e30f, xB2 = -1e30f;
    if (vA) {
        const float* ap = asrc + (size_t)sA * 3;
        xA0 = lrelu(ap[0] + ad0); xA1 = lrelu(ap[1] + ad1); xA2 = lrelu(ap[2] + ad2);
    }
    if (vB) {
        const float* ap = asrc + (size_t)sB * 3;
        xB0 = lrelu(ap[0] + ad0); xB1 = lrelu(ap[1] + ad1); xB2 = lrelu(ap[2] + ad2);
    }
    float m0 = fmaxf(xA0, xB0), m1 = fmaxf(xA1, xB1), m2 = fmaxf(xA2, xB2);
#pragma unroll
    for (int off = 32; off; off >>= 1) {
        m0 = fmaxf(m0, __shfl_xor(m0, off));
        m1 = fmaxf(m1, __shfl_xor(m1, off));
        m2 = fmaxf(m2, __shfl_xor(m2, off));
    }
    float eA0 = expf(xA0 - m0), eA1 = expf(xA1 - m1), eA2 = expf(xA2 - m2);
    float eB0 = expf(xB0 - m0), eB1 = expf(xB1 - m1), eB2 = expf(xB2 - m2);
    float t0 = eA0 + eB0, t1 = eA1 + eB1, t2 = eA2 + eB2;
#pragma unroll
    for (int off = 32; off; off >>= 1) {
        t0 += __shfl_xor(t0, off);
        t1 += __shfl_xor(t1, off);
        t2 += __shfl_xor(t2, off);
    }
    float r0 = 1.f / (t0 + 1e-16f);
    float r1 = 1.f / (t1 + 1e-16f);
    float r2 = 1.f / (t2 + 1e-16f);
    float wA0 = eA0 * r0, wA1 = eA1 * r1, wA2 = eA2 * r2;
    float wB0 = eB0 * r0, wB1 = eB1 * r1, wB2 = eB2 * r2;

    float a00 = 0.f, a01 = 0.f, a10 = 0.f, a11 = 0.f, a20 = 0.f, a21 = 0.f;
    int d0 = deg < 64 ? deg : 64;
    for (int j = 0; j < d0; ++j) {
        int   s  = __builtin_amdgcn_readlane(sA, j);
        float w0 = rdlane_f(wA0, j);
        float w1 = rdlane_f(wA1, j);
        float w2 = rdlane_f(wA2, j);
        const u16* hp = h + (size_t)s * HC;
        ushort2 h0 = *reinterpret_cast<const ushort2*>(hp + lane * 2);
        ushort2 h1 = *reinterpret_cast<const ushort2*>(hp + 128 + lane * 2);
        ushort2 h2 = *reinterpret_cast<const ushort2*>(hp + 256 + lane * 2);
        a00 += bf2f(h0.x) * w0; a01 += bf2f(h0.y) * w0;
        a10 += bf2f(h1.x) * w1; a11 += bf2f(h1.y) * w1;
        a20 += bf2f(h2.x) * w2; a21 += bf2f(h2.y) * w2;
    }
    for (int j = 64; j < deg; ++j) {            // rare spill path (deg > 64)
        int   s  = __builtin_amdgcn_readlane(sB, j - 64);
        float w0 = rdlane_f(wB0, j - 64);
        float w1 = rdlane_f(wB1, j - 64);
        float w2 = rdlane_f(wB2, j - 64);
        const u16* hp = h + (size_t)s * HC;
        ushort2 h0 = *reinterpret_cast<const ushort2*>(hp + lane * 2);
        ushort2 h1 = *reinterpret_cast<const ushort2*>(hp + 128 + lane * 2);
        ushort2 h2 = *reinterpret_cast<const ushort2*>(hp + 256 + lane * 2);
        a00 += bf2f(h0.x) * w0; a01 += bf2f(h0.y) * w0;
        a10 += bf2f(h1.x) * w1; a11 += bf2f(h1.y) * w1;
        a20 += bf2f(h2.x) * w2; a21 += bf2f(h2.y) * w2;
    }

    size_t base = (size_t)nd * HC;
    float o[6];
    int   c[3] = { lane * 2, 128 + lane * 2, 256 + lane * 2 };
    o[0] = a00 + bias[c[0]];     o[1] = a01 + bias[c[0] + 1];
    o[2] = a10 + bias[c[1]];     o[3] = a11 + bias[c[1] + 1];
    o[4] = a20 + bias[c[2]];     o[5] = a21 + bias[c[2] + 1];
#pragma unroll
    for (int k = 0; k < 6; ++k) o[k] = o[k] > 0.f ? o[k] : 0.f;   // fused ReLU
    if (fOut) {
#pragma unroll
        for (int k = 0; k < 3; ++k)
            *reinterpret_cast<float2*>(fOut + base + c[k]) = make_float2(o[2 * k], o[2 * k + 1]);
    } else {
#pragma unroll
        for (int k = 0; k < 3; ++k) {
            u16 hx = f2bf(o[2 * k]), hy = f2bf(o[2 * k + 1]);
            ushort2 hv = { hx, hy };
            ushort2 lv = { f2bf(o[2 * k] - bf2f(hx)), f2bf(o[2 * k + 1] - bf2f(hy)) };
            *reinterpret_cast<ushort2*>(hOut + base + c[k]) = hv;
            *reinterpret_cast<ushort2*>(lOut + base + c[k]) = lv;
        }
    }
}

// ---------------- final classifier: out[M,40] = A[M,384] @ W[384,40] + b ----------------
__global__ __launch_bounds__(256) void out_gemm(const float* __restrict__ A,
                                                const float* __restrict__ W,
                                                const float* __restrict__ b,
                                                float* __restrict__ out)
{
    int gid = blockIdx.x * 256 + threadIdx.x;
    int r  = gid / 10;
    int c4 = (gid - r * 10) * 4;
    if (r >= N_NODES) return;
    const float* ar = A + (size_t)r * HC;
    float ax = 0.f, ay = 0.f, az = 0.f, aw = 0.f;
#pragma unroll 2
    for (int k = 0; k < HC; k += 4) {
        float4 a  = *reinterpret_cast<const float4*>(ar + k);
        float4 w0 = *reinterpret_cast<const float4*>(W + (size_t)(k + 0) * NCLS + c4);
        float4 w1 = *reinterpret_cast<const float4*>(W + (size_t)(k + 1) * NCLS + c4);
        float4 w2 = *reinterpret_cast<const float4*>(W + (size_t)(k + 2) * NCLS + c4);
        float4 w3 = *reinterpret_cast<const float4*>(W + (size_t)(k + 3) * NCLS + c4);
        ax += a.x * w0.x + a.y * w1.x + a.z * w2.x + a.w * w3.x;
        ay += a.x * w0.y + a.y * w1.y + a.z * w2.y + a.w * w3.y;
        az += a.x * w0.z + a.y * w1.z + a.z * w2.z + a.w * w3.z;
        aw += a.x * w0.w + a.y * w1.w + a.z * w2.w + a.w * w3.w;
    }
    float4 bb = *reinterpret_cast<const float4*>(b + c4);
    float4 o = make_float4(ax + bb.x, ay + bb.y, az + bb.z, aw + bb.w);
    *reinterpret_cast<float4*>(out + (size_t)r * NCLS + c4) = o;
}

extern "C" void kernel_launch(void* const* d_in, const int* in_sizes, int n_in,
                              void* d_out, int out_size, void* d_ws, size_t ws_size,
                              hipStream_t stream)
{
    const float* x    = (const float*)d_in[0];
    const int*   ei   = (const int*)d_in[1];     // int32 (harness ships integer inputs as int32)
    const float* W1   = (const float*)d_in[2];
    const float* as1  = (const float*)d_in[3];
    const float* ad1  = (const float*)d_in[4];
    const float* b1   = (const float*)d_in[5];
    const float* W2   = (const float*)d_in[6];
    const float* as2  = (const float*)d_in[7];
    const float* ad2  = (const float*)d_in[8];
    const float* b2   = (const float*)d_in[9];
    const float* outW = (const float*)d_in[10];
    const float* outb = (const float*)d_in[11];
    float* out = (float*)d_out;

    // ---- workspace layout ----
    // region0 (76.8 MB): hB bf16 [N,384] (gemm output, both layers; only 38.4 MB used)
    // region2 (76.8 MB), lifetimes disjoint:
    //   xh/xl bf16 [N,256] each (dead after gemm1)
    //   aggH/aggL bf16 [N,384] each (written agg1, dead after gemm2)
    //   bufA fp32 [N,384] (written agg2, read out_gemm)
    u16*   hB   = (u16*)d_ws;
    char*  reg2 = (char*)d_ws + (size_t)N_NODES * HC * 4;
    u16*   xh   = (u16*)reg2;
    u16*   xl   = xh + (size_t)N_NODES * IN_DIM;
    u16*   aggH = (u16*)reg2;
    u16*   aggL = aggH + (size_t)N_NODES * HC;
    float* bufA = (float*)reg2;
    char*  tail = reg2 + (size_t)N_NODES * HC * 4;
    u16* W1tH = (u16*)tail;                              // [256/8][384][8]
    u16* W1tL = W1tH + (size_t)IN_DIM * HC;
    u16* W2tH = W1tL + (size_t)IN_DIM * HC;              // [384/8][384][8]
    u16* W2tL = W2tH + (size_t)HC * HC;
    float* asrc = (float*)(W2tL + (size_t)HC * HC);
    float* adst = asrc + (size_t)N_NODES * HEADS;
    int*   cnt    = (int*)(adst + (size_t)N_NODES * HEADS);
    int*   bucket = cnt + N_NODES;

    hipMemsetAsync(cnt, 0, N_NODES * sizeof(int), stream);
    count_scatter<<<(ET + 255) / 256, 256, 0, stream>>>(ei, cnt, bucket);

    split_kernel<<<(N_NODES * IN_DIM / 4 + 255) / 256, 256, 0, stream>>>(x, xh, xl, N_NODES * IN_DIM / 4);
    split_wt<<<(IN_DIM * HC + 255) / 256, 256, 0, stream>>>(W1, W1tH, W1tL, IN_DIM);
    split_wt<<<(HC * HC + 255) / 256, 256, 0, stream>>>(W2, W2tH, W2tL, HC);

    dim3 gg(HC / BN, (N_NODES + BM - 1) / BM);   // (3, 391)
    // ---- layer 1 ----
    gemm_mfma<<<gg, 256, 0, stream>>>(xh, xl, W1tH, W1tL, hB, N_NODES, IN_DIM);
    scores_kernel<<<(N_NODES * HEADS + 3) / 4, 256, 0, stream>>>(hB, as1, ad1, asrc, adst);
    aggregate_kernel<<<(N_NODES + 3) / 4, 256, 0, stream>>>(hB, asrc, adst, cnt, bucket, b1,
                                                            aggH, aggL, nullptr);
    // ---- layer 2 ----
    gemm_mfma<<<gg, 256, 0, stream>>>(aggH, aggL, W2tH, W2tL, hB, N_NODES, HC);
    scores_kernel<<<(N_NODES * HEADS + 3) / 4, 256, 0, stream>>>(hB, as2, ad2, asrc, adst);
    aggregate_kernel<<<(N_NODES + 3) / 4, 256, 0, stream>>>(hB, asrc, adst, cnt, bucket, b2,
                                                            nullptr, nullptr, bufA);
    // ---- classifier ----
    out_gemm<<<(N_NODES * 10 + 255) / 256, 256, 0, stream>>>(bufA, outW, outb, out);
}

// Round 8
// 592.591 us; speedup vs baseline: 2.0138x; 1.1481x over previous
//
#include <hip/hip_runtime.h>
#include <cstdint>
#include <cstddef>

typedef unsigned short u16;
typedef unsigned int   u32;
typedef __attribute__((ext_vector_type(8))) short bf16x8;
typedef __attribute__((ext_vector_type(4))) float f32x4;

#define N_NODES 50000
#define N_EDGES 800000
#define ET (N_EDGES + N_NODES)   // edges + self loops = 850000
#define IN_DIM 256
#define HID 128
#define HEADS 3
#define HC 384                   // HEADS * HID
#define NCLS 40
#define CAP 96                   // per-node in-edge bucket capacity (deg ~ Poisson(17), max@50K nodes ~45)

// ---------------- bf16 helpers (RNE) ----------------
__device__ __forceinline__ u16 f2bf(float f) {
    union { float f; u32 u; } x; x.f = f;
    u32 r = x.u + 0x7fffu + ((x.u >> 16) & 1u);
    return (u16)(r >> 16);
}
__device__ __forceinline__ float bf2f(u16 b) {
    union { u32 u; float f; } x; x.u = ((u32)b) << 16; return x.f;
}

__device__ __forceinline__ void gload_lds16(const void* g, void* l) {
    __builtin_amdgcn_global_load_lds((const __attribute__((address_space(1))) void*)g,
                                     (__attribute__((address_space(3))) void*)l, 16, 0, 0);
}

__device__ __forceinline__ float rdlane_f(float v, int l) {
    return __int_as_float(__builtin_amdgcn_readlane(__float_as_int(v), l));
}

// ---------------- CSR-by-destination build (bucketed, no sort/scan) ----------------
__global__ __launch_bounds__(256) void count_scatter(const int* __restrict__ ei,
                                                     int* __restrict__ cnt,
                                                     int* __restrict__ bucket)
{
    int e = blockIdx.x * 256 + threadIdx.x;
    if (e >= ET) return;
    int s, d;
    if (e < N_EDGES) { s = ei[e]; d = ei[N_EDGES + e]; }
    else             { s = e - N_EDGES; d = s; }          // self loop
    int pos = atomicAdd(&cnt[d], 1);
    if (pos < CAP) bucket[d * CAP + pos] = s;
}

// ---------------- fp32 -> (hi,lo) bf16 split, flat, 4 elems/thread ----------------
__global__ __launch_bounds__(256) void split_kernel(const float* __restrict__ in,
                                                    u16* __restrict__ hi,
                                                    u16* __restrict__ lo, int n4)
{
    int i = blockIdx.x * 256 + threadIdx.x;
    if (i >= n4) return;
    float4 v = reinterpret_cast<const float4*>(in)[i];
    ushort4 h, l;
    h.x = f2bf(v.x); l.x = f2bf(v.x - bf2f(h.x));
    h.y = f2bf(v.y); l.y = f2bf(v.y - bf2f(h.y));
    h.z = f2bf(v.z); l.z = f2bf(v.z - bf2f(h.z));
    h.w = f2bf(v.w); l.w = f2bf(v.w - bf2f(h.w));
    reinterpret_cast<ushort4*>(hi)[i] = h;
    reinterpret_cast<ushort4*>(lo)[i] = l;
}

// ---------------- W[K][N] -> fragment-order split Wt{h,l}[K/8][HC][8] ----------------
__global__ __launch_bounds__(256) void split_wt(const float* __restrict__ W,
                                                u16* __restrict__ WtH,
                                                u16* __restrict__ WtL, int K)
{
    int idx = blockIdx.x * 256 + threadIdx.x;
    if (idx >= K * HC) return;
    int k = idx / HC, n = idx - k * HC;
    float v = W[idx];
    u16 h = f2bf(v);
    size_t o = ((size_t)(k >> 3) * HC + n) * 8 + (k & 7);
    WtH[o] = h;
    WtL[o] = f2bf(v - bf2f(h));
}

// ---------------- Wo[384][40] -> fragment-order split [384/8][64][8], cols 40-63 zero ----
__global__ __launch_bounds__(256) void split_wo(const float* __restrict__ Wo,
                                                u16* __restrict__ WoH,
                                                u16* __restrict__ WoL)
{
    int idx = blockIdx.x * 256 + threadIdx.x;
    if (idx >= HC * 64) return;
    int k = idx >> 6, n = idx & 63;
    float v = (n < NCLS) ? Wo[k * NCLS + n] : 0.f;
    u16 h = f2bf(v);
    size_t o = ((size_t)(k >> 3) * 64 + n) * 8 + (k & 7);
    WoH[o] = h;
    WoL[o] = f2bf(v - bf2f(h));
}

// ---------------- split-bf16 MFMA GEMM: Cb[M,HC] = bf16(A[M,K] @ W^T) ----------------
// A: double-buffered LDS (global_load_lds, [kgrp][row][8] layout).
// B: direct global->reg fragment loads from [K/8][HC][8] (L2-resident weights).
#define BM 128
#define BN 128
#define BK 32
__global__ __launch_bounds__(256) void gemm_mfma(const u16* __restrict__ Ah, const u16* __restrict__ Al,
                                                 const u16* __restrict__ Bh, const u16* __restrict__ Bl,
                                                 u16* __restrict__ Cb, int M, int K)
{
    __shared__ u16 sAh0[BM * BK], sAl0[BM * BK], sAh1[BM * BK], sAl1[BM * BK];
    const int tid = threadIdx.x;
    const int ln  = tid & 63;
    const int wv  = tid >> 6;
    const int bm  = blockIdx.y * BM;
    const int bn  = blockIdx.x * BN;
    const int wm  = (wv >> 1) * 64;
    const int wn  = (wv & 1) * 64;
    const int kg  = ln >> 4;
    const int lr  = ln & 15;
    const int nK  = K >> 5;     // K-steps of 32 (8 or 12, always even)

    f32x4 acc[4][4] = {};

    auto stage = [&](u16* dAh, u16* dAl, int ko) {
#pragma unroll
        for (int rnd = 0; rnd < 2; ++rnd) {
            int c   = rnd * 256 + wv * 64 + ln;     // chunk id 0..511
            int row = c & 127;
            int kgp = c >> 7;
            int ldsOff = (rnd * 256 + wv * 64) * 8; // wave-uniform (elements)
            int ar = bm + row; if (ar >= M) ar = M - 1;
            size_t off = (size_t)ar * K + ko + kgp * 8;
            gload_lds16(Ah + off, dAh + ldsOff);
            gload_lds16(Al + off, dAl + ldsOff);
        }
    };

    auto step = [&](const u16* curAh, const u16* curAl, u16* nxtAh, u16* nxtAl,
                    int kt, bool pref) {
        const int ko = kt * BK;
        bf16x8 bhf[4], blf[4];
        size_t bb = ((size_t)((ko >> 3) + kg) * HC + bn + wn + lr) * 8;
#pragma unroll
        for (int ni = 0; ni < 4; ++ni) {
            bhf[ni] = *reinterpret_cast<const bf16x8*>(Bh + bb + ni * 128);
            blf[ni] = *reinterpret_cast<const bf16x8*>(Bl + bb + ni * 128);
        }
        if (pref) stage(nxtAh, nxtAl, ko + BK);
#pragma unroll
        for (int mi = 0; mi < 4; ++mi) {
            int off = (kg * 128 + wm + mi * 16 + lr) * 8;
            bf16x8 ah = *reinterpret_cast<const bf16x8*>(curAh + off);
            bf16x8 al = *reinterpret_cast<const bf16x8*>(curAl + off);
#pragma unroll
            for (int ni = 0; ni < 4; ++ni) {
                acc[mi][ni] = __builtin_amdgcn_mfma_f32_16x16x32_bf16(ah, bhf[ni], acc[mi][ni], 0, 0, 0);
                acc[mi][ni] = __builtin_amdgcn_mfma_f32_16x16x32_bf16(al, bhf[ni], acc[mi][ni], 0, 0, 0);
                acc[mi][ni] = __builtin_amdgcn_mfma_f32_16x16x32_bf16(ah, blf[ni], acc[mi][ni], 0, 0, 0);
            }
        }
    };

    stage(sAh0, sAl0, 0);
    for (int kt = 0; kt < nK; kt += 2) {
        __syncthreads();
        step(sAh0, sAl0, sAh1, sAl1, kt, true);
        __syncthreads();
        step(sAh1, sAl1, sAh0, sAl0, kt + 1, kt + 2 < nK);
    }

    // C/D layout (m89-verified): col = lane&15, row = (lane>>4)*4 + i; store bf16
#pragma unroll
    for (int mi = 0; mi < 4; ++mi) {
#pragma unroll
        for (int i = 0; i < 4; ++i) {
            int r = bm + wm + mi * 16 + kg * 4 + i;
            if (r < M) {
#pragma unroll
                for (int ni = 0; ni < 4; ++ni) {
                    Cb[(size_t)r * HC + bn + wn + ni * 16 + lr] = f2bf(acc[mi][ni][i]);
                }
            }
        }
    }
}

// ---------------- classifier on MFMA: out[M,40] = A[M,384] @ Wo + b ----------------
// A split bf16 [M][384]; Wo split fragment-order [48][64][8] (cols 40-63 zero).
// 4 waves x 64 rows (OM=256), one 64-col N-tile, K = 12 steps of 32, single-buffer LDS.
#define OM 256
__global__ __launch_bounds__(256) void out_mfma(const u16* __restrict__ Ah, const u16* __restrict__ Al,
                                                const u16* __restrict__ WoH, const u16* __restrict__ WoL,
                                                const float* __restrict__ b,
                                                float* __restrict__ out)
{
    __shared__ u16 sAh[OM * BK], sAl[OM * BK];
    const int tid = threadIdx.x;
    const int ln  = tid & 63;
    const int wv  = tid >> 6;
    const int bm  = blockIdx.x * OM;
    const int kg  = ln >> 4;
    const int lr  = ln & 15;

    f32x4 acc[4][4] = {};

    for (int kt = 0; kt < HC / BK; ++kt) {
        const int ko = kt * BK;
        __syncthreads();                         // previous step's reads done
        // stage A tile [kgrp][row][8], rows 0..255: 1024 chunks / 256 threads = 4 rounds
#pragma unroll
        for (int rnd = 0; rnd < 4; ++rnd) {
            int c   = rnd * 256 + tid;           // wave-uniform base + lane
            int row = c & 255;
            int kgp = c >> 8;
            int ldsOff = (rnd * 256 + wv * 64) * 8;
            int ar = bm + row; if (ar >= N_NODES) ar = N_NODES - 1;
            size_t off = (size_t)ar * HC + ko + kgp * 8;
            gload_lds16(Ah + off, sAh + ldsOff);
            gload_lds16(Al + off, sAl + ldsOff);
        }
        __syncthreads();                         // staged data visible

        bf16x8 bhf[4], blf[4];
        size_t bb = ((size_t)((ko >> 3) + kg) * 64 + lr) * 8;
#pragma unroll
        for (int ni = 0; ni < 4; ++ni) {
            bhf[ni] = *reinterpret_cast<const bf16x8*>(WoH + bb + ni * 128);
            blf[ni] = *reinterpret_cast<const bf16x8*>(WoL + bb + ni * 128);
        }
#pragma unroll
        for (int mi = 0; mi < 4; ++mi) {
            int off = (kg * 256 + wv * 64 + mi * 16 + lr) * 8;
            bf16x8 ah = *reinterpret_cast<const bf16x8*>(sAh + off);
            bf16x8 al = *reinterpret_cast<const bf16x8*>(sAl + off);
#pragma unroll
            for (int ni = 0; ni < 4; ++ni) {
                acc[mi][ni] = __builtin_amdgcn_mfma_f32_16x16x32_bf16(ah, bhf[ni], acc[mi][ni], 0, 0, 0);
                acc[mi][ni] = __builtin_amdgcn_mfma_f32_16x16x32_bf16(al, bhf[ni], acc[mi][ni], 0, 0, 0);
                acc[mi][ni] = __builtin_amdgcn_mfma_f32_16x16x32_bf16(ah, blf[ni], acc[mi][ni], 0, 0, 0);
            }
        }
    }

    // C/D: col = ni*16 + (lane&15), row = wv*64 + mi*16 + (lane>>4)*4 + i
#pragma unroll
    for (int mi = 0; mi < 4; ++mi) {
#pragma unroll
        for (int i = 0; i < 4; ++i) {
            int r = bm + wv * 64 + mi * 16 + kg * 4 + i;
            if (r < N_NODES) {
#pragma unroll
                for (int ni = 0; ni < 4; ++ni) {
                    int col = ni * 16 + lr;
                    if (col < NCLS)
                        out[(size_t)r * NCLS + col] = acc[mi][ni][i] + b[col];
                }
            }
        }
    }
}

// ---------------- per-(node,head) attention scores from bf16 h ----------------
__global__ __launch_bounds__(256) void scores_kernel(const u16* __restrict__ h,
                                                     const float* __restrict__ att_s,
                                                     const float* __restrict__ att_d,
                                                     float* __restrict__ asrc,
                                                     float* __restrict__ adst)
{
    int gid = blockIdx.x * 256 + threadIdx.x;
    int wid = gid >> 6;
    int lane = gid & 63;
    if (wid >= N_NODES * HEADS) return;
    int nd = wid / 3;
    int hd = wid - nd * 3;
    const u16* hp = h + (size_t)nd * HC + hd * HID;
    float v0 = bf2f(hp[lane]), v1 = bf2f(hp[lane + 64]);
    float s = v0 * att_s[hd * HID + lane] + v1 * att_s[hd * HID + lane + 64];
    float d = v0 * att_d[hd * HID + lane] + v1 * att_d[hd * HID + lane + 64];
#pragma unroll
    for (int off = 32; off; off >>= 1) {
        s += __shfl_xor(s, off);
        d += __shfl_xor(d, off);
    }
    if (lane == 0) { asrc[wid] = s; adst[wid] = d; }
}

__device__ __forceinline__ float lrelu(float x) { return x > 0.f ? x : 0.2f * x; }

// ---------------- per-node softmax + weighted aggregation (+bias +ReLU) ----------------
// one wave per destination node; lane-parallel weights, readlane broadcast in phase 2.
// bf16 gather (768 B/edge); output always split hi/lo bf16.
__global__ __launch_bounds__(256) void aggregate_kernel(const u16* __restrict__ h,
                                                        const float* __restrict__ asrc,
                                                        const float* __restrict__ adst,
                                                        const int* __restrict__ cnt,
                                                        const int* __restrict__ bucket,
                                                        const float* __restrict__ bias,
                                                        u16* __restrict__ hOut,
                                                        u16* __restrict__ lOut)
{
    int wv = threadIdx.x >> 6;
    int lane = threadIdx.x & 63;
    int nd = blockIdx.x * 4 + wv;
    if (nd >= N_NODES) return;
    int deg = cnt[nd];
    if (deg > CAP) deg = CAP;
    const int* eb = bucket + nd * CAP;
    float ad0 = adst[nd * 3 + 0], ad1 = adst[nd * 3 + 1], ad2 = adst[nd * 3 + 2];

    bool vA = lane < deg, vB = lane + 64 < deg;
    int sA = vA ? eb[lane] : 0;
    int sB = vB ? eb[lane + 64] : 0;
    float xA0 = -1e30f, xA1 = -1e30f, xA2 = -1e30f;
    float xB0 = -1e30f, xB1 = -1e30f, xB2 = -1e30f;
    if (vA) {
        const float* ap = asrc + (size_t)sA * 3;
        xA0 = lrelu(ap[0] + ad0); xA1 = lrelu(ap[1] + ad1); xA2 = lrelu(ap[2] + ad2);
    }
    if (vB) {
        const float* ap = asrc + (size_t)sB * 3;
        xB0 = lrelu(ap[0] + ad0); xB1 = lrelu(ap[1] + ad1); xB2 = lrelu(ap[2] + ad2);
    }
    float m0 = fmaxf(xA0, xB0), m1 = fmaxf(xA1, xB1), m2 = fmaxf(xA2, xB2);
#pragma unroll
    for (int off = 32; off; off >>= 1) {
        m0 = fmaxf(m0, __shfl_xor(m0, off));
        m1 = fmaxf(m1, __shfl_xor(m1, off));
        m2 = fmaxf(m2, __shfl_xor(m2, off));
    }
    float eA0 = expf(xA0 - m0), eA1 = expf(xA1 - m1), eA2 = expf(xA2 - m2);
    float eB0 = expf(xB0 - m0), eB1 = expf(xB1 - m1), eB2 = expf(xB2 - m2);
    float t0 = eA0 + eB0, t1 = eA1 + eB1, t2 = eA2 + eB2;
#pragma unroll
    for (int off = 32; off; off >>= 1) {
        t0 += __shfl_xor(t0, off);
        t1 += __shfl_xor(t1, off);
        t2 += __shfl_xor(t2, off);
    }
    float r0 = 1.f / (t0 + 1e-16f);
    float r1 = 1.f / (t1 + 1e-16f);
    float r2 = 1.f / (t2 + 1e-16f);
    float wA0 = eA0 * r0, wA1 = eA1 * r1, wA2 = eA2 * r2;
    float wB0 = eB0 * r0, wB1 = eB1 * r1, wB2 = eB2 * r2;

    float a00 = 0.f, a01 = 0.f, a10 = 0.f, a11 = 0.f, a20 = 0.f, a21 = 0.f;
    int d0 = deg < 64 ? deg : 64;
    for (int j = 0; j < d0; ++j) {
        int   s  = __builtin_amdgcn_readlane(sA, j);
        float w0 = rdlane_f(wA0, j);
        float w1 = rdlane_f(wA1, j);
        float w2 = rdlane_f(wA2, j);
        const u16* hp = h + (size_t)s * HC;
        ushort2 h0 = *reinterpret_cast<const ushort2*>(hp + lane * 2);
        ushort2 h1 = *reinterpret_cast<const ushort2*>(hp + 128 + lane * 2);
        ushort2 h2 = *reinterpret_cast<const ushort2*>(hp + 256 + lane * 2);
        a00 += bf2f(h0.x) * w0; a01 += bf2f(h0.y) * w0;
        a10 += bf2f(h1.x) * w1; a11 += bf2f(h1.y) * w1;
        a20 += bf2f(h2.x) * w2; a21 += bf2f(h2.y) * w2;
    }
    for (int j = 64; j < deg; ++j) {            // rare spill path (deg > 64)
        int   s  = __builtin_amdgcn_readlane(sB, j - 64);
        float w0 = rdlane_f(wB0, j - 64);
        float w1 = rdlane_f(wB1, j - 64);
        float w2 = rdlane_f(wB2, j - 64);
        const u16* hp = h + (size_t)s * HC;
        ushort2 h0 = *reinterpret_cast<const ushort2*>(hp + lane * 2);
        ushort2 h1 = *reinterpret_cast<const ushort2*>(hp + 128 + lane * 2);
        ushort2 h2 = *reinterpret_cast<const ushort2*>(hp + 256 + lane * 2);
        a00 += bf2f(h0.x) * w0; a01 += bf2f(h0.y) * w0;
        a10 += bf2f(h1.x) * w1; a11 += bf2f(h1.y) * w1;
        a20 += bf2f(h2.x) * w2; a21 += bf2f(h2.y) * w2;
    }

    size_t base = (size_t)nd * HC;
    float o[6];
    int   c[3] = { lane * 2, 128 + lane * 2, 256 + lane * 2 };
    o[0] = a00 + bias[c[0]];     o[1] = a01 + bias[c[0] + 1];
    o[2] = a10 + bias[c[1]];     o[3] = a11 + bias[c[1] + 1];
    o[4] = a20 + bias[c[2]];     o[5] = a21 + bias[c[2] + 1];
#pragma unroll
    for (int k = 0; k < 6; ++k) o[k] = o[k] > 0.f ? o[k] : 0.f;   // fused ReLU
#pragma unroll
    for (int k = 0; k < 3; ++k) {
        u16 hx = f2bf(o[2 * k]), hy = f2bf(o[2 * k + 1]);
        ushort2 hv = { hx, hy };
        ushort2 lv = { f2bf(o[2 * k] - bf2f(hx)), f2bf(o[2 * k + 1] - bf2f(hy)) };
        *reinterpret_cast<ushort2*>(hOut + base + c[k]) = hv;
        *reinterpret_cast<ushort2*>(lOut + base + c[k]) = lv;
    }
}

extern "C" void kernel_launch(void* const* d_in, const int* in_sizes, int n_in,
                              void* d_out, int out_size, void* d_ws, size_t ws_size,
                              hipStream_t stream)
{
    const float* x    = (const float*)d_in[0];
    const int*   ei   = (const int*)d_in[1];     // int32 (harness ships integer inputs as int32)
    const float* W1   = (const float*)d_in[2];
    const float* as1  = (const float*)d_in[3];
    const float* ad1  = (const float*)d_in[4];
    const float* b1   = (const float*)d_in[5];
    const float* W2   = (const float*)d_in[6];
    const float* as2  = (const float*)d_in[7];
    const float* ad2  = (const float*)d_in[8];
    const float* b2   = (const float*)d_in[9];
    const float* outW = (const float*)d_in[10];
    const float* outb = (const float*)d_in[11];
    float* out = (float*)d_out;

    // ---- workspace layout ----
    // region0 (76.8 MB): hB bf16 [N,384] (gemm output, both layers)
    // region2 (76.8 MB), lifetimes disjoint:
    //   xh/xl bf16 [N,256] each (dead after gemm1)
    //   aggH/aggL bf16 [N,384] each (agg1 -> gemm2; agg2 -> out_mfma)
    u16*   hB   = (u16*)d_ws;
    char*  reg2 = (char*)d_ws + (size_t)N_NODES * HC * 4;
    u16*   xh   = (u16*)reg2;
    u16*   xl   = xh + (size_t)N_NODES * IN_DIM;
    u16*   aggH = (u16*)reg2;
    u16*   aggL = aggH + (size_t)N_NODES * HC;
    char*  tail = reg2 + (size_t)N_NODES * HC * 4;
    u16* W1tH = (u16*)tail;                              // [256/8][384][8]
    u16* W1tL = W1tH + (size_t)IN_DIM * HC;
    u16* W2tH = W1tL + (size_t)IN_DIM * HC;              // [384/8][384][8]
    u16* W2tL = W2tH + (size_t)HC * HC;
    u16* WoH  = W2tL + (size_t)HC * HC;                  // [384/8][64][8]
    u16* WoL  = WoH + (size_t)HC * 64;
    float* asrc = (float*)(WoL + (size_t)HC * 64);
    float* adst = asrc + (size_t)N_NODES * HEADS;
    int*   cnt    = (int*)(adst + (size_t)N_NODES * HEADS);
    int*   bucket = cnt + N_NODES;

    hipMemsetAsync(cnt, 0, N_NODES * sizeof(int), stream);
    count_scatter<<<(ET + 255) / 256, 256, 0, stream>>>(ei, cnt, bucket);

    split_kernel<<<(N_NODES * IN_DIM / 4 + 255) / 256, 256, 0, stream>>>(x, xh, xl, N_NODES * IN_DIM / 4);
    split_wt<<<(IN_DIM * HC + 255) / 256, 256, 0, stream>>>(W1, W1tH, W1tL, IN_DIM);
    split_wt<<<(HC * HC + 255) / 256, 256, 0, stream>>>(W2, W2tH, W2tL, HC);
    split_wo<<<(HC * 64 + 255) / 256, 256, 0, stream>>>(outW, WoH, WoL);

    dim3 gg(HC / BN, (N_NODES + BM - 1) / BM);   // (3, 391)
    // ---- layer 1 ----
    gemm_mfma<<<gg, 256, 0, stream>>>(xh, xl, W1tH, W1tL, hB, N_NODES, IN_DIM);
    scores_kernel<<<(N_NODES * HEADS + 3) / 4, 256, 0, stream>>>(hB, as1, ad1, asrc, adst);
    aggregate_kernel<<<(N_NODES + 3) / 4, 256, 0, stream>>>(hB, asrc, adst, cnt, bucket, b1,
                                                            aggH, aggL);
    // ---- layer 2 ----
    gemm_mfma<<<gg, 256, 0, stream>>>(aggH, aggL, W2tH, W2tL, hB, N_NODES, HC);
    scores_kernel<<<(N_NODES * HEADS + 3) / 4, 256, 0, stream>>>(hB, as2, ad2, asrc, adst);
    aggregate_kernel<<<(N_NODES + 3) / 4, 256, 0, stream>>>(hB, asrc, adst, cnt, bucket, b2,
                                                            aggH, aggL);
    // ---- classifier ----
    out_mfma<<<(N_NODES + OM - 1) / OM, 256, 0, stream>>>(aggH, aggL, WoH, WoL, outb, out);
}

// Round 10
// 533.469 us; speedup vs baseline: 2.2370x; 1.1108x over previous
//
#include <hip/hip_runtime.h>
#include <cstdint>
#include <cstddef>

typedef unsigned short u16;
typedef unsigned int   u32;
typedef __attribute__((ext_vector_type(8))) short bf16x8;
typedef __attribute__((ext_vector_type(4))) float f32x4;

#define N_NODES 50000
#define N_EDGES 800000
#define ET (N_EDGES + N_NODES)   // edges + self loops = 850000
#define IN_DIM 256
#define HID 128
#define HEADS 3
#define HC 384                   // HEADS * HID
#define NCLS 40
#define CAP 96                   // per-node in-edge bucket capacity (deg ~ Poisson(17), max@50K nodes ~45)

// ---------------- bf16 helpers (RNE) ----------------
__device__ __forceinline__ u16 f2bf(float f) {
    union { float f; u32 u; } x; x.f = f;
    u32 r = x.u + 0x7fffu + ((x.u >> 16) & 1u);
    return (u16)(r >> 16);
}
__device__ __forceinline__ float bf2f(u16 b) {
    union { u32 u; float f; } x; x.u = ((u32)b) << 16; return x.f;
}

__device__ __forceinline__ void gload_lds16(const void* g, void* l) {
    __builtin_amdgcn_global_load_lds((const __attribute__((address_space(1))) void*)g,
                                     (__attribute__((address_space(3))) void*)l, 16, 0, 0);
}

__device__ __forceinline__ float rdlane_f(float v, int l) {
    return __int_as_float(__builtin_amdgcn_readlane(__float_as_int(v), l));
}

// ---------------- CSR-by-destination build (bucketed, no sort/scan) ----------------
__global__ __launch_bounds__(256) void count_scatter(const int* __restrict__ ei,
                                                     int* __restrict__ cnt,
                                                     int* __restrict__ bucket)
{
    int e = blockIdx.x * 256 + threadIdx.x;
    if (e >= ET) return;
    int s, d;
    if (e < N_EDGES) { s = ei[e]; d = ei[N_EDGES + e]; }
    else             { s = e - N_EDGES; d = s; }          // self loop
    int pos = atomicAdd(&cnt[d], 1);
    if (pos < CAP) bucket[d * CAP + pos] = s;
}

// ---------------- fp32 -> bf16 convert (single), 4 elems/thread ----------------
__global__ __launch_bounds__(256) void cvt_bf16(const float* __restrict__ in,
                                                u16* __restrict__ o, int n4)
{
    int i = blockIdx.x * 256 + threadIdx.x;
    if (i >= n4) return;
    float4 v = reinterpret_cast<const float4*>(in)[i];
    ushort4 h = { f2bf(v.x), f2bf(v.y), f2bf(v.z), f2bf(v.w) };
    reinterpret_cast<ushort4*>(o)[i] = h;
}

// ---------------- W[K][N] -> fragment-order split Wt{h,l}[K/8][HC][8] ----------------
__global__ __launch_bounds__(256) void split_wt(const float* __restrict__ W,
                                                u16* __restrict__ WtH,
                                                u16* __restrict__ WtL, int K)
{
    int idx = blockIdx.x * 256 + threadIdx.x;
    if (idx >= K * HC) return;
    int k = idx / HC, n = idx - k * HC;
    float v = W[idx];
    u16 h = f2bf(v);
    size_t o = ((size_t)(k >> 3) * HC + n) * 8 + (k & 7);
    WtH[o] = h;
    WtL[o] = f2bf(v - bf2f(h));
}

// ---------------- Wo[384][40] -> fragment-order split [384/8][64][8], cols 40-63 zero ----
__global__ __launch_bounds__(256) void split_wo(const float* __restrict__ Wo,
                                                u16* __restrict__ WoH,
                                                u16* __restrict__ WoL)
{
    int idx = blockIdx.x * 256 + threadIdx.x;
    if (idx >= HC * 64) return;
    int k = idx >> 6, n = idx & 63;
    float v = (n < NCLS) ? Wo[k * NCLS + n] : 0.f;
    u16 h = f2bf(v);
    size_t o = ((size_t)(k >> 3) * 64 + n) * 8 + (k & 7);
    WoH[o] = h;
    WoL[o] = f2bf(v - bf2f(h));
}

// ---------------- 2-term MFMA GEMM: Cb[M,HC] = bf16( bf16A[M,K] @ (Wh+Wl)^T ) ----------------
// A: single bf16, double-buffered LDS ([kgrp][row][8] layout via global_load_lds).
// B: direct global->reg fragment loads from [K/8][HC][8] (L2-resident split weights).
// acc = Ah*Bh + Ah*Bl — exact product of bf16(A) with fp32-accurate W.
#define BM 128
#define BN 128
#define BK 32
__global__ __launch_bounds__(256) void gemm_mfma(const u16* __restrict__ A,
                                                 const u16* __restrict__ Bh, const u16* __restrict__ Bl,
                                                 u16* __restrict__ Cb, int M, int K)
{
    __shared__ u16 sA0[BM * BK], sA1[BM * BK];
    const int tid = threadIdx.x;
    const int ln  = tid & 63;
    const int wv  = tid >> 6;
    const int bm  = blockIdx.y * BM;
    const int bn  = blockIdx.x * BN;
    const int wm  = (wv >> 1) * 64;
    const int wn  = (wv & 1) * 64;
    const int kg  = ln >> 4;
    const int lr  = ln & 15;
    const int nK  = K >> 5;     // K-steps of 32 (8 or 12, always even)

    f32x4 acc[4][4] = {};

    auto stage = [&](u16* dA, int ko) {
#pragma unroll
        for (int rnd = 0; rnd < 2; ++rnd) {
            int c   = rnd * 256 + wv * 64 + ln;     // chunk id 0..511
            int row = c & 127;
            int kgp = c >> 7;
            int ldsOff = (rnd * 256 + wv * 64) * 8; // wave-uniform (elements)
            int ar = bm + row; if (ar >= M) ar = M - 1;
            gload_lds16(A + (size_t)ar * K + ko + kgp * 8, dA + ldsOff);
        }
    };

    auto step = [&](const u16* curA, u16* nxtA, int kt, bool pref) {
        const int ko = kt * BK;
        bf16x8 bhf[4], blf[4];
        size_t bb = ((size_t)((ko >> 3) + kg) * HC + bn + wn + lr) * 8;
#pragma unroll
        for (int ni = 0; ni < 4; ++ni) {
            bhf[ni] = *reinterpret_cast<const bf16x8*>(Bh + bb + ni * 128);
            blf[ni] = *reinterpret_cast<const bf16x8*>(Bl + bb + ni * 128);
        }
        if (pref) stage(nxtA, ko + BK);
#pragma unroll
        for (int mi = 0; mi < 4; ++mi) {
            bf16x8 ah = *reinterpret_cast<const bf16x8*>(curA + (kg * 128 + wm + mi * 16 + lr) * 8);
#pragma unroll
            for (int ni = 0; ni < 4; ++ni) {
                acc[mi][ni] = __builtin_amdgcn_mfma_f32_16x16x32_bf16(ah, bhf[ni], acc[mi][ni], 0, 0, 0);
                acc[mi][ni] = __builtin_amdgcn_mfma_f32_16x16x32_bf16(ah, blf[ni], acc[mi][ni], 0, 0, 0);
            }
        }
    };

    stage(sA0, 0);
    for (int kt = 0; kt < nK; kt += 2) {
        __syncthreads();
        step(sA0, sA1, kt, true);
        __syncthreads();
        step(sA1, sA0, kt + 1, kt + 2 < nK);
    }

    // C/D layout (m89-verified): col = lane&15, row = (lane>>4)*4 + i; store bf16
#pragma unroll
    for (int mi = 0; mi < 4; ++mi) {
#pragma unroll
        for (int i = 0; i < 4; ++i) {
            int r = bm + wm + mi * 16 + kg * 4 + i;
            if (r < M) {
#pragma unroll
                for (int ni = 0; ni < 4; ++ni) {
                    Cb[(size_t)r * HC + bn + wn + ni * 16 + lr] = f2bf(acc[mi][ni][i]);
                }
            }
        }
    }
}

// ---------------- classifier on MFMA: out[M,40] = (Ah+Al)[M,384] @ Wo + b ----------------
// A split hi/lo (classifier input keeps near-fp32 precision: gain to output is ~1).
#define OM 256
__global__ __launch_bounds__(256) void out_mfma(const u16* __restrict__ Ah, const u16* __restrict__ Al,
                                                const u16* __restrict__ WoH, const u16* __restrict__ WoL,
                                                const float* __restrict__ b,
                                                float* __restrict__ out)
{
    __shared__ u16 sAh[OM * BK], sAl[OM * BK];
    const int tid = threadIdx.x;
    const int ln  = tid & 63;
    const int wv  = tid >> 6;
    const int bm  = blockIdx.x * OM;
    const int kg  = ln >> 4;
    const int lr  = ln & 15;

    f32x4 acc[4][4] = {};

    for (int kt = 0; kt < HC / BK; ++kt) {
        const int ko = kt * BK;
        __syncthreads();
#pragma unroll
        for (int rnd = 0; rnd < 4; ++rnd) {
            int c   = rnd * 256 + wv * 64 + ln;
            int row = c & 255;
            int kgp = c >> 8;
            int ldsOff = (rnd * 256 + wv * 64) * 8;
            int ar = bm + row; if (ar >= N_NODES) ar = N_NODES - 1;
            size_t off = (size_t)ar * HC + ko + kgp * 8;
            gload_lds16(Ah + off, sAh + ldsOff);
            gload_lds16(Al + off, sAl + ldsOff);
        }
        __syncthreads();

        bf16x8 bhf[4], blf[4];
        size_t bb = ((size_t)((ko >> 3) + kg) * 64 + lr) * 8;
#pragma unroll
        for (int ni = 0; ni < 4; ++ni) {
            bhf[ni] = *reinterpret_cast<const bf16x8*>(WoH + bb + ni * 128);
            blf[ni] = *reinterpret_cast<const bf16x8*>(WoL + bb + ni * 128);
        }
#pragma unroll
        for (int mi = 0; mi < 4; ++mi) {
            int off = (kg * 256 + wv * 64 + mi * 16 + lr) * 8;
            bf16x8 ah = *reinterpret_cast<const bf16x8*>(sAh + off);
            bf16x8 al = *reinterpret_cast<const bf16x8*>(sAl + off);
#pragma unroll
            for (int ni = 0; ni < 4; ++ni) {
                acc[mi][ni] = __builtin_amdgcn_mfma_f32_16x16x32_bf16(ah, bhf[ni], acc[mi][ni], 0, 0, 0);
                acc[mi][ni] = __builtin_amdgcn_mfma_f32_16x16x32_bf16(al, bhf[ni], acc[mi][ni], 0, 0, 0);
                acc[mi][ni] = __builtin_amdgcn_mfma_f32_16x16x32_bf16(ah, blf[ni], acc[mi][ni], 0, 0, 0);
            }
        }
    }

#pragma unroll
    for (int mi = 0; mi < 4; ++mi) {
#pragma unroll
        for (int i = 0; i < 4; ++i) {
            int r = bm + wv * 64 + mi * 16 + kg * 4 + i;
            if (r < N_NODES) {
#pragma unroll
                for (int ni = 0; ni < 4; ++ni) {
                    int col = ni * 16 + lr;
                    if (col < NCLS)
                        out[(size_t)r * NCLS + col] = acc[mi][ni][i] + b[col];
                }
            }
        }
    }
}

// ---------------- per-(node,head) attention scores from bf16 h ----------------
__global__ __launch_bounds__(256) void scores_kernel(const u16* __restrict__ h,
                                                     const float* __restrict__ att_s,
                                                     const float* __restrict__ att_d,
                                                     float* __restrict__ asrc,
                                                     float* __restrict__ adst)
{
    int gid = blockIdx.x * 256 + threadIdx.x;
    int wid = gid >> 6;
    int lane = gid & 63;
    if (wid >= N_NODES * HEADS) return;
    int nd = wid / 3;
    int hd = wid - nd * 3;
    const u16* hp = h + (size_t)nd * HC + hd * HID;
    float v0 = bf2f(hp[lane]), v1 = bf2f(hp[lane + 64]);
    float s = v0 * att_s[hd * HID + lane] + v1 * att_s[hd * HID + lane + 64];
    float d = v0 * att_d[hd * HID + lane] + v1 * att_d[hd * HID + lane + 64];
#pragma unroll
    for (int off = 32; off; off >>= 1) {
        s += __shfl_xor(s, off);
        d += __shfl_xor(d, off);
    }
    if (lane == 0) { asrc[wid] = s; adst[wid] = d; }
}

__device__ __forceinline__ float lrelu(float x) { return x > 0.f ? x : 0.2f * x; }

// ---------------- per-node softmax + weighted aggregation (+bias +ReLU) ----------------
// one wave per destination node; lane-parallel weights, readlane broadcast in phase 2.
// bf16 gather (768 B/edge); output single bf16 (lOut==nullptr) or split hi/lo.
__global__ __launch_bounds__(256) void aggregate_kernel(const u16* __restrict__ h,
                                                        const float* __restrict__ asrc,
                                                        const float* __restrict__ adst,
                                                        const int* __restrict__ cnt,
                                                        const int* __restrict__ bucket,
                                                        const float* __restrict__ bias,
                                                        u16* __restrict__ hOut,
                                                        u16* __restrict__ lOut)
{
    int wv = threadIdx.x >> 6;
    int lane = threadIdx.x & 63;
    int nd = blockIdx.x * 4 + wv;
    if (nd >= N_NODES) return;
    int deg = cnt[nd];
    if (deg > CAP) deg = CAP;
    const int* eb = bucket + nd * CAP;
    float ad0 = adst[nd * 3 + 0], ad1 = adst[nd * 3 + 1], ad2 = adst[nd * 3 + 2];

    bool vA = lane < deg, vB = lane + 64 < deg;
    int sA = vA ? eb[lane] : 0;
    int sB = vB ? eb[lane + 64] : 0;
    float xA0 = -1e30f, xA1 = -1e30f, xA2 = -1e30f;
    float xB0 = -1e30f, xB1 = -1e30f, xB2 = -1e30f;
    if (vA) {
        const float* ap = asrc + (size_t)sA * 3;
        xA0 = lrelu(ap[0] + ad0); xA1 = lrelu(ap[1] + ad1); xA2 = lrelu(ap[2] + ad2);
    }
    if (vB) {
        const float* ap = asrc + (size_t)sB * 3;
        xB0 = lrelu(ap[0] + ad0); xB1 = lrelu(ap[1] + ad1); xB2 = lrelu(ap[2] + ad2);
    }
    float m0 = fmaxf(xA0, xB0), m1 = fmaxf(xA1, xB1), m2 = fmaxf(xA2, xB2);
#pragma unroll
    for (int off = 32; off; off >>= 1) {
        m0 = fmaxf(m0, __shfl_xor(m0, off));
        m1 = fmaxf(m1, __shfl_xor(m1, off));
        m2 = fmaxf(m2, __shfl_xor(m2, off));
    }
    float eA0 = expf(xA0 - m0), eA1 = expf(xA1 - m1), eA2 = expf(xA2 - m2);
    float eB0 = expf(xB0 - m0), eB1 = expf(xB1 - m1), eB2 = expf(xB2 - m2);
    float t0 = eA0 + eB0, t1 = eA1 + eB1, t2 = eA2 + eB2;
#pragma unroll
    for (int off = 32; off; off >>= 1) {
        t0 += __shfl_xor(t0, off);
        t1 += __shfl_xor(t1, off);
        t2 += __shfl_xor(t2, off);
    }
    float r0 = 1.f / (t0 + 1e-16f);
    float r1 = 1.f / (t1 + 1e-16f);
    float r2 = 1.f / (t2 + 1e-16f);
    float wA0 = eA0 * r0, wA1 = eA1 * r1, wA2 = eA2 * r2;
    float wB0 = eB0 * r0, wB1 = eB1 * r1, wB2 = eB2 * r2;

    float a00 = 0.f, a01 = 0.f, a10 = 0.f, a11 = 0.f, a20 = 0.f, a21 = 0.f;
    int d0 = deg < 64 ? deg : 64;
    for (int j = 0; j < d0; ++j) {
        int   s  = __builtin_amdgcn_readlane(sA, j);
        float w0 = rdlane_f(wA0, j);
        float w1 = rdlane_f(wA1, j);
        float w2 = rdlane_f(wA2, j);
        const u16* hp = h + (size_t)s * HC;
        ushort2 h0 = *reinterpret_cast<const ushort2*>(hp + lane * 2);
        ushort2 h1 = *reinterpret_cast<const ushort2*>(hp + 128 + lane * 2);
        ushort2 h2 = *reinterpret_cast<const ushort2*>(hp + 256 + lane * 2);
        a00 += bf2f(h0.x) * w0; a01 += bf2f(h0.y) * w0;
        a10 += bf2f(h1.x) * w1; a11 += bf2f(h1.y) * w1;
        a20 += bf2f(h2.x) * w2; a21 += bf2f(h2.y) * w2;
    }
    for (int j = 64; j < deg; ++j) {            // rare spill path (deg > 64)
        int   s  = __builtin_amdgcn_readlane(sB, j - 64);
        float w0 = rdlane_f(wB0, j - 64);
        float w1 = rdlane_f(wB1, j - 64);
        float w2 = rdlane_f(wB2, j - 64);
        const u16* hp = h + (size_t)s * HC;
        ushort2 h0 = *reinterpret_cast<const ushort2*>(hp + lane * 2);
        ushort2 h1 = *reinterpret_cast<const ushort2*>(hp + 128 + lane * 2);
        ushort2 h2 = *reinterpret_cast<const ushort2*>(hp + 256 + lane * 2);
        a00 += bf2f(h0.x) * w0; a01 += bf2f(h0.y) * w0;
        a10 += bf2f(h1.x) * w1; a11 += bf2f(h1.y) * w1;
        a20 += bf2f(h2.x) * w2; a21 += bf2f(h2.y) * w2;
    }

    size_t base = (size_t)nd * HC;
    float o[6];
    int   c[3] = { lane * 2, 128 + lane * 2, 256 + lane * 2 };
    o[0] = a00 + bias[c[0]];     o[1] = a01 + bias[c[0] + 1];
    o[2] = a10 + bias[c[1]];     o[3] = a11 + bias[c[1] + 1];
    o[4] = a20 + bias[c[2]];     o[5] = a21 + bias[c[2] + 1];
#pragma unroll
    for (int k = 0; k < 6; ++k) o[k] = o[k] > 0.f ? o[k] : 0.f;   // fused ReLU
    if (lOut) {
#pragma unroll
        for (int k = 0; k < 3; ++k) {
            u16 hx = f2bf(o[2 * k]), hy = f2bf(o[2 * k + 1]);
            ushort2 hv = { hx, hy };
            ushort2 lv = { f2bf(o[2 * k] - bf2f(hx)), f2bf(o[2 * k + 1] - bf2f(hy)) };
            *reinterpret_cast<ushort2*>(hOut + base + c[k]) = hv;
            *reinterpret_cast<ushort2*>(lOut + base + c[k]) = lv;
        }
    } else {
#pragma unroll
        for (int k = 0; k < 3; ++k) {
            ushort2 hv = { f2bf(o[2 * k]), f2bf(o[2 * k + 1]) };
            *reinterpret_cast<ushort2*>(hOut + base + c[k]) = hv;
        }
    }
}

extern "C" void kernel_launch(void* const* d_in, const int* in_sizes, int n_in,
                              void* d_out, int out_size, void* d_ws, size_t ws_size,
                              hipStream_t stream)
{
    const float* x    = (const float*)d_in[0];
    const int*   ei   = (const int*)d_in[1];     // int32 (harness ships integer inputs as int32)
    const float* W1   = (const float*)d_in[2];
    const float* as1  = (const float*)d_in[3];
    const float* ad1  = (const float*)d_in[4];
    const float* b1   = (const float*)d_in[5];
    const float* W2   = (const float*)d_in[6];
    const float* as2  = (const float*)d_in[7];
    const float* ad2  = (const float*)d_in[8];
    const float* b2   = (const float*)d_in[9];
    const float* outW = (const float*)d_in[10];
    const float* outb = (const float*)d_in[11];
    float* out = (float*)d_out;

    // ---- workspace layout ----
    // hB   bf16 [N,384]: gemm output (both layers), gather source
    // aggH bf16 [N,384]: agg output hi (layer1: single; layer2: hi of split)
    // aggL bf16 [N,384]: agg2 lo (classifier input precision)
    // xB   bf16 [N,256]: aliases aggH (dead before agg1 writes)
    u16*   hB   = (u16*)d_ws;
    u16*   aggH = hB + (size_t)N_NODES * HC;
    u16*   aggL = aggH + (size_t)N_NODES * HC;
    u16*   xB   = aggH;                                  // alias: xB dead before agg1
    char*  tail = (char*)(aggL + (size_t)N_NODES * HC);
    u16* W1tH = (u16*)tail;                              // [256/8][384][8]
    u16* W1tL = W1tH + (size_t)IN_DIM * HC;
    u16* W2tH = W1tL + (size_t)IN_DIM * HC;              // [384/8][384][8]
    u16* W2tL = W2tH + (size_t)HC * HC;
    u16* WoH  = W2tL + (size_t)HC * HC;                  // [384/8][64][8]
    u16* WoL  = WoH + (size_t)HC * 64;
    float* asrc = (float*)(WoL + (size_t)HC * 64);
    float* adst = asrc + (size_t)N_NODES * HEADS;
    int*   cnt    = (int*)(adst + (size_t)N_NODES * HEADS);
    int*   bucket = cnt + N_NODES;

    hipMemsetAsync(cnt, 0, N_NODES * sizeof(int), stream);
    count_scatter<<<(ET + 255) / 256, 256, 0, stream>>>(ei, cnt, bucket);

    cvt_bf16<<<(N_NODES * IN_DIM / 4 + 255) / 256, 256, 0, stream>>>(x, xB, N_NODES * IN_DIM / 4);
    split_wt<<<(IN_DIM * HC + 255) / 256, 256, 0, stream>>>(W1, W1tH, W1tL, IN_DIM);
    split_wt<<<(HC * HC + 255) / 256, 256, 0, stream>>>(W2, W2tH, W2tL, HC);
    split_wo<<<(HC * 64 + 255) / 256, 256, 0, stream>>>(outW, WoH, WoL);

    dim3 gg(HC / BN, (N_NODES + BM - 1) / BM);   // (3, 391)
    // ---- layer 1 ----
    gemm_mfma<<<gg, 256, 0, stream>>>(xB, W1tH, W1tL, hB, N_NODES, IN_DIM);
    scores_kernel<<<(N_NODES * HEADS + 3) / 4, 256, 0, stream>>>(hB, as1, ad1, asrc, adst);
    aggregate_kernel<<<(N_NODES + 3) / 4, 256, 0, stream>>>(hB, asrc, adst, cnt, bucket, b1,
                                                            aggH, nullptr);
    // ---- layer 2 ----
    gemm_mfma<<<gg, 256, 0, stream>>>(aggH, W2tH, W2tL, hB, N_NODES, HC);
    scores_kernel<<<(N_NODES * HEADS + 3) / 4, 256, 0, stream>>>(hB, as2, ad2, asrc, adst);
    aggregate_kernel<<<(N_NODES + 3) / 4, 256, 0, stream>>>(hB, asrc, adst, cnt, bucket, b2,
                                                            aggH, aggL);
    // ---- classifier ----
    out_mfma<<<(N_NODES + OM - 1) / OM, 256, 0, stream>>>(aggH, aggL, WoH, WoL, outb, out);
}

// Round 11
// 505.069 us; speedup vs baseline: 2.3628x; 1.0562x over previous
//
#include <hip/hip_runtime.h>
#include <cstdint>
#include <cstddef>

typedef unsigned short u16;
typedef unsigned int   u32;
typedef __attribute__((ext_vector_type(8))) short bf16x8;
typedef __attribute__((ext_vector_type(4))) float f32x4;

#define N_NODES 50000
#define N_EDGES 800000
#define ET (N_EDGES + N_NODES)   // edges + self loops = 850000
#define IN_DIM 256
#define HID 128
#define HEADS 3
#define HC 384                   // HEADS * HID
#define NCLS 40
#define CAP 96                   // per-node in-edge bucket capacity (deg ~ Poisson(17), max@50K nodes ~45)

// ---------------- bf16 helpers (RNE) ----------------
__device__ __forceinline__ u16 f2bf(float f) {
    union { float f; u32 u; } x; x.f = f;
    u32 r = x.u + 0x7fffu + ((x.u >> 16) & 1u);
    return (u16)(r >> 16);
}
__device__ __forceinline__ float bf2f(u16 b) {
    union { u32 u; float f; } x; x.u = ((u32)b) << 16; return x.f;
}

__device__ __forceinline__ void gload_lds16(const void* g, void* l) {
    __builtin_amdgcn_global_load_lds((const __attribute__((address_space(1))) void*)g,
                                     (__attribute__((address_space(3))) void*)l, 16, 0, 0);
}

__device__ __forceinline__ float rdlane_f(float v, int l) {
    return __int_as_float(__builtin_amdgcn_readlane(__float_as_int(v), l));
}

// ---------------- CSR-by-destination build (bucketed, no sort/scan) ----------------
__global__ __launch_bounds__(256) void count_scatter(const int* __restrict__ ei,
                                                     int* __restrict__ cnt,
                                                     int* __restrict__ bucket)
{
    int e = blockIdx.x * 256 + threadIdx.x;
    if (e >= ET) return;
    int s, d;
    if (e < N_EDGES) { s = ei[e]; d = ei[N_EDGES + e]; }
    else             { s = e - N_EDGES; d = s; }          // self loop
    int pos = atomicAdd(&cnt[d], 1);
    if (pos < CAP) bucket[d * CAP + pos] = s;
}

// ---------------- fp32 -> bf16 convert (single), 4 elems/thread ----------------
__global__ __launch_bounds__(256) void cvt_bf16(const float* __restrict__ in,
                                                u16* __restrict__ o, int n4)
{
    int i = blockIdx.x * 256 + threadIdx.x;
    if (i >= n4) return;
    float4 v = reinterpret_cast<const float4*>(in)[i];
    ushort4 h = { f2bf(v.x), f2bf(v.y), f2bf(v.z), f2bf(v.w) };
    reinterpret_cast<ushort4*>(o)[i] = h;
}

// ---------------- W[K][N] -> fragment-order split Wt{h,l}[K/8][HC][8] ----------------
__global__ __launch_bounds__(256) void split_wt(const float* __restrict__ W,
                                                u16* __restrict__ WtH,
                                                u16* __restrict__ WtL, int K)
{
    int idx = blockIdx.x * 256 + threadIdx.x;
    if (idx >= K * HC) return;
    int k = idx / HC, n = idx - k * HC;
    float v = W[idx];
    u16 h = f2bf(v);
    size_t o = ((size_t)(k >> 3) * HC + n) * 8 + (k & 7);
    WtH[o] = h;
    WtL[o] = f2bf(v - bf2f(h));
}

// ---------------- Wo[384][40] -> fragment-order split [384/8][64][8], cols 40-63 zero ----
__global__ __launch_bounds__(256) void split_wo(const float* __restrict__ Wo,
                                                u16* __restrict__ WoH,
                                                u16* __restrict__ WoL)
{
    int idx = blockIdx.x * 256 + threadIdx.x;
    if (idx >= HC * 64) return;
    int k = idx >> 6, n = idx & 63;
    float v = (n < NCLS) ? Wo[k * NCLS + n] : 0.f;
    u16 h = f2bf(v);
    size_t o = ((size_t)(k >> 3) * 64 + n) * 8 + (k & 7);
    WoH[o] = h;
    WoL[o] = f2bf(v - bf2f(h));
}

// ---------------- 2-term MFMA GEMM + fused attention scores ----------------
// Cb[M,HC] = bf16( bf16A[M,K] @ (Wh+Wl)^T ); since BN==HID==128, each block's
// column range is exactly one head -> per-row scores a_src/a_dst computed from
// fp32 acc in the epilogue (shfl-reduce over lr group, LDS combine of wave halves).
#define BM 128
#define BN 128
#define BK 32
__global__ __launch_bounds__(256) void gemm_mfma(const u16* __restrict__ A,
                                                 const u16* __restrict__ Bh, const u16* __restrict__ Bl,
                                                 const float* __restrict__ att_s,
                                                 const float* __restrict__ att_d,
                                                 float* __restrict__ asrc,
                                                 float* __restrict__ adst,
                                                 u16* __restrict__ Cb, int M, int K)
{
    __shared__ u16 sA0[BM * BK], sA1[BM * BK];
    __shared__ float sS[2][BM], sD[2][BM];
    const int tid = threadIdx.x;
    const int ln  = tid & 63;
    const int wv  = tid >> 6;
    const int bm  = blockIdx.y * BM;
    const int bn  = blockIdx.x * BN;
    const int wm  = (wv >> 1) * 64;
    const int wn  = (wv & 1) * 64;
    const int kg  = ln >> 4;
    const int lr  = ln & 15;
    const int nK  = K >> 5;     // K-steps of 32 (8 or 12, always even)

    f32x4 acc[4][4] = {};

    auto stage = [&](u16* dA, int ko) {
#pragma unroll
        for (int rnd = 0; rnd < 2; ++rnd) {
            int c   = rnd * 256 + wv * 64 + ln;     // chunk id 0..511
            int row = c & 127;
            int kgp = c >> 7;
            int ldsOff = (rnd * 256 + wv * 64) * 8; // wave-uniform (elements)
            int ar = bm + row; if (ar >= M) ar = M - 1;
            gload_lds16(A + (size_t)ar * K + ko + kgp * 8, dA + ldsOff);
        }
    };

    auto step = [&](const u16* curA, u16* nxtA, int kt, bool pref) {
        const int ko = kt * BK;
        bf16x8 bhf[4], blf[4];
        size_t bb = ((size_t)((ko >> 3) + kg) * HC + bn + wn + lr) * 8;
#pragma unroll
        for (int ni = 0; ni < 4; ++ni) {
            bhf[ni] = *reinterpret_cast<const bf16x8*>(Bh + bb + ni * 128);
            blf[ni] = *reinterpret_cast<const bf16x8*>(Bl + bb + ni * 128);
        }
        if (pref) stage(nxtA, ko + BK);
#pragma unroll
        for (int mi = 0; mi < 4; ++mi) {
            bf16x8 ah = *reinterpret_cast<const bf16x8*>(curA + (kg * 128 + wm + mi * 16 + lr) * 8);
#pragma unroll
            for (int ni = 0; ni < 4; ++ni) {
                acc[mi][ni] = __builtin_amdgcn_mfma_f32_16x16x32_bf16(ah, bhf[ni], acc[mi][ni], 0, 0, 0);
                acc[mi][ni] = __builtin_amdgcn_mfma_f32_16x16x32_bf16(ah, blf[ni], acc[mi][ni], 0, 0, 0);
            }
        }
    };

    stage(sA0, 0);
    for (int kt = 0; kt < nK; kt += 2) {
        __syncthreads();
        step(sA0, sA1, kt, true);
        __syncthreads();
        step(sA1, sA0, kt + 1, kt + 2 < nK);
    }

    // ---- C write: C/D layout col = lane&15, row = (lane>>4)*4 + i ----
#pragma unroll
    for (int mi = 0; mi < 4; ++mi) {
#pragma unroll
        for (int i = 0; i < 4; ++i) {
            int r = bm + wm + mi * 16 + kg * 4 + i;
            if (r < M) {
#pragma unroll
                for (int ni = 0; ni < 4; ++ni) {
                    Cb[(size_t)r * HC + bn + wn + ni * 16 + lr] = f2bf(acc[mi][ni][i]);
                }
            }
        }
    }

    // ---- fused scores: this block's cols == head hd ----
    const int hd = blockIdx.x;
    float as_[4], ad_[4];
#pragma unroll
    for (int ni = 0; ni < 4; ++ni) {
        int colh = wn + ni * 16 + lr;
        as_[ni] = att_s[hd * HID + colh];
        ad_[ni] = att_d[hd * HID + colh];
    }
#pragma unroll
    for (int mi = 0; mi < 4; ++mi) {
#pragma unroll
        for (int i = 0; i < 4; ++i) {
            float ps = acc[mi][0][i] * as_[0] + acc[mi][1][i] * as_[1]
                     + acc[mi][2][i] * as_[2] + acc[mi][3][i] * as_[3];
            float pd = acc[mi][0][i] * ad_[0] + acc[mi][1][i] * ad_[1]
                     + acc[mi][2][i] * ad_[2] + acc[mi][3][i] * ad_[3];
#pragma unroll
            for (int off = 1; off < 16; off <<= 1) {
                ps += __shfl_xor(ps, off);
                pd += __shfl_xor(pd, off);
            }
            if (lr == 0) {
                int rl = wm + mi * 16 + kg * 4 + i;
                sS[wv & 1][rl] = ps;
                sD[wv & 1][rl] = pd;
            }
        }
    }
    __syncthreads();
    if (tid < BM) {
        int r = bm + tid;
        if (r < M) {
            asrc[r * 3 + hd] = sS[0][tid] + sS[1][tid];
            adst[r * 3 + hd] = sD[0][tid] + sD[1][tid];
        }
    }
}

// ---------------- classifier on MFMA: out[M,40] = (Ah+Al)[M,384] @ Wo + b ----------------
#define OM 256
__global__ __launch_bounds__(256) void out_mfma(const u16* __restrict__ Ah, const u16* __restrict__ Al,
                                                const u16* __restrict__ WoH, const u16* __restrict__ WoL,
                                                const float* __restrict__ b,
                                                float* __restrict__ out)
{
    __shared__ u16 sAh[OM * BK], sAl[OM * BK];
    const int tid = threadIdx.x;
    const int ln  = tid & 63;
    const int wv  = tid >> 6;
    const int bm  = blockIdx.x * OM;
    const int kg  = ln >> 4;
    const int lr  = ln & 15;

    f32x4 acc[4][4] = {};

    for (int kt = 0; kt < HC / BK; ++kt) {
        const int ko = kt * BK;
        __syncthreads();
#pragma unroll
        for (int rnd = 0; rnd < 4; ++rnd) {
            int c   = rnd * 256 + wv * 64 + ln;
            int row = c & 255;
            int kgp = c >> 8;
            int ldsOff = (rnd * 256 + wv * 64) * 8;
            int ar = bm + row; if (ar >= N_NODES) ar = N_NODES - 1;
            size_t off = (size_t)ar * HC + ko + kgp * 8;
            gload_lds16(Ah + off, sAh + ldsOff);
            gload_lds16(Al + off, sAl + ldsOff);
        }
        __syncthreads();

        bf16x8 bhf[4], blf[4];
        size_t bb = ((size_t)((ko >> 3) + kg) * 64 + lr) * 8;
#pragma unroll
        for (int ni = 0; ni < 4; ++ni) {
            bhf[ni] = *reinterpret_cast<const bf16x8*>(WoH + bb + ni * 128);
            blf[ni] = *reinterpret_cast<const bf16x8*>(WoL + bb + ni * 128);
        }
#pragma unroll
        for (int mi = 0; mi < 4; ++mi) {
            int off = (kg * 256 + wv * 64 + mi * 16 + lr) * 8;
            bf16x8 ah = *reinterpret_cast<const bf16x8*>(sAh + off);
            bf16x8 al = *reinterpret_cast<const bf16x8*>(sAl + off);
#pragma unroll
            for (int ni = 0; ni < 4; ++ni) {
                acc[mi][ni] = __builtin_amdgcn_mfma_f32_16x16x32_bf16(ah, bhf[ni], acc[mi][ni], 0, 0, 0);
                acc[mi][ni] = __builtin_amdgcn_mfma_f32_16x16x32_bf16(al, bhf[ni], acc[mi][ni], 0, 0, 0);
                acc[mi][ni] = __builtin_amdgcn_mfma_f32_16x16x32_bf16(ah, blf[ni], acc[mi][ni], 0, 0, 0);
            }
        }
    }

#pragma unroll
    for (int mi = 0; mi < 4; ++mi) {
#pragma unroll
        for (int i = 0; i < 4; ++i) {
            int r = bm + wv * 64 + mi * 16 + kg * 4 + i;
            if (r < N_NODES) {
#pragma unroll
                for (int ni = 0; ni < 4; ++ni) {
                    int col = ni * 16 + lr;
                    if (col < NCLS)
                        out[(size_t)r * NCLS + col] = acc[mi][ni][i] + b[col];
                }
            }
        }
    }
}

__device__ __forceinline__ float lrelu(float x) { return x > 0.f ? x : 0.2f * x; }

// ---------------- per-node softmax + weighted aggregation (+bias +ReLU) ----------------
// one wave per destination node; lane-parallel weights, readlane broadcast in phase 2.
// Gather: 2 loads/edge/lane (ushort4 ch0-255 + ushort2 ch256-383); per-lane head
// select via cndmask between wave-uniform w0/w1. 768 B/wave/edge unchanged.
__global__ __launch_bounds__(256) void aggregate_kernel(const u16* __restrict__ h,
                                                        const float* __restrict__ asrc,
                                                        const float* __restrict__ adst,
                                                        const int* __restrict__ cnt,
                                                        const int* __restrict__ bucket,
                                                        const float* __restrict__ bias,
                                                        u16* __restrict__ hOut,
                                                        u16* __restrict__ lOut)
{
    int wv = threadIdx.x >> 6;
    int lane = threadIdx.x & 63;
    int nd = blockIdx.x * 4 + wv;
    if (nd >= N_NODES) return;
    int deg = cnt[nd];
    if (deg > CAP) deg = CAP;
    const int* eb = bucket + nd * CAP;
    float ad0 = adst[nd * 3 + 0], ad1 = adst[nd * 3 + 1], ad2 = adst[nd * 3 + 2];

    bool vA = lane < deg, vB = lane + 64 < deg;
    int sA = vA ? eb[lane] : 0;
    int sB = vB ? eb[lane + 64] : 0;
    float xA0 = -1e30f, xA1 = -1e30f, xA2 = -1e30f;
    float xB0 = -1e30f, xB1 = -1e30f, xB2 = -1e30f;
    if (vA) {
        const float* ap = asrc + (size_t)sA * 3;
        xA0 = lrelu(ap[0] + ad0); xA1 = lrelu(ap[1] + ad1); xA2 = lrelu(ap[2] + ad2);
    }
    if (vB) {
        const float* ap = asrc + (size_t)sB * 3;
        xB0 = lrelu(ap[0] + ad0); xB1 = lrelu(ap[1] + ad1); xB2 = lrelu(ap[2] + ad2);
    }
    float m0 = fmaxf(xA0, xB0), m1 = fmaxf(xA1, xB1), m2 = fmaxf(xA2, xB2);
#pragma unroll
    for (int off = 32; off; off >>= 1) {
        m0 = fmaxf(m0, __shfl_xor(m0, off));
        m1 = fmaxf(m1, __shfl_xor(m1, off));
        m2 = fmaxf(m2, __shfl_xor(m2, off));
    }
    float eA0 = expf(xA0 - m0), eA1 = expf(xA1 - m1), eA2 = expf(xA2 - m2);
    float eB0 = expf(xB0 - m0), eB1 = expf(xB1 - m1), eB2 = expf(xB2 - m2);
    float t0 = eA0 + eB0, t1 = eA1 + eB1, t2 = eA2 + eB2;
#pragma unroll
    for (int off = 32; off; off >>= 1) {
        t0 += __shfl_xor(t0, off);
        t1 += __shfl_xor(t1, off);
        t2 += __shfl_xor(t2, off);
    }
    float r0 = 1.f / (t0 + 1e-16f);
    float r1 = 1.f / (t1 + 1e-16f);
    float r2 = 1.f / (t2 + 1e-16f);
    float wA0 = eA0 * r0, wA1 = eA1 * r1, wA2 = eA2 * r2;
    float wB0 = eB0 * r0, wB1 = eB1 * r1, wB2 = eB2 * r2;

    // lane owns ch {4l..4l+3} (heads 0/1) and ch {256+2l, 256+2l+1} (head 2)
    float b0 = 0.f, b1 = 0.f, b2 = 0.f, b3 = 0.f, b4 = 0.f, b5 = 0.f;
    int d0 = deg < 64 ? deg : 64;
#pragma unroll 2
    for (int j = 0; j < d0; ++j) {
        int   s  = __builtin_amdgcn_readlane(sA, j);
        float w0 = rdlane_f(wA0, j);
        float w1 = rdlane_f(wA1, j);
        float w2 = rdlane_f(wA2, j);
        float wh = lane < 32 ? w0 : w1;
        const u16* hp = h + (size_t)s * HC;
        ushort4 v4 = *reinterpret_cast<const ushort4*>(hp + lane * 4);
        ushort2 v2 = *reinterpret_cast<const ushort2*>(hp + 256 + lane * 2);
        b0 += bf2f(v4.x) * wh; b1 += bf2f(v4.y) * wh;
        b2 += bf2f(v4.z) * wh; b3 += bf2f(v4.w) * wh;
        b4 += bf2f(v2.x) * w2; b5 += bf2f(v2.y) * w2;
    }
    for (int j = 64; j < deg; ++j) {            // rare spill path (deg > 64)
        int   s  = __builtin_amdgcn_readlane(sB, j - 64);
        float w0 = rdlane_f(wB0, j - 64);
        float w1 = rdlane_f(wB1, j - 64);
        float w2 = rdlane_f(wB2, j - 64);
        float wh = lane < 32 ? w0 : w1;
        const u16* hp = h + (size_t)s * HC;
        ushort4 v4 = *reinterpret_cast<const ushort4*>(hp + lane * 4);
        ushort2 v2 = *reinterpret_cast<const ushort2*>(hp + 256 + lane * 2);
        b0 += bf2f(v4.x) * wh; b1 += bf2f(v4.y) * wh;
        b2 += bf2f(v4.z) * wh; b3 += bf2f(v4.w) * wh;
        b4 += bf2f(v2.x) * w2; b5 += bf2f(v2.y) * w2;
    }

    // epilogue: +bias, ReLU, store
    size_t base = (size_t)nd * HC;
    int c4 = lane * 4, c2 = 256 + lane * 2;
    float4 bb4 = *reinterpret_cast<const float4*>(bias + c4);
    float2 bb2 = *reinterpret_cast<const float2*>(bias + c2);
    float o0 = b0 + bb4.x, o1 = b1 + bb4.y, o2 = b2 + bb4.z, o3 = b3 + bb4.w;
    float o4 = b4 + bb2.x, o5 = b5 + bb2.y;
    o0 = o0 > 0.f ? o0 : 0.f;  o1 = o1 > 0.f ? o1 : 0.f;
    o2 = o2 > 0.f ? o2 : 0.f;  o3 = o3 > 0.f ? o3 : 0.f;
    o4 = o4 > 0.f ? o4 : 0.f;  o5 = o5 > 0.f ? o5 : 0.f;
    ushort4 hv4 = { f2bf(o0), f2bf(o1), f2bf(o2), f2bf(o3) };
    ushort2 hv2 = { f2bf(o4), f2bf(o5) };
    *reinterpret_cast<ushort4*>(hOut + base + c4) = hv4;
    *reinterpret_cast<ushort2*>(hOut + base + c2) = hv2;
    if (lOut) {
        ushort4 lv4 = { f2bf(o0 - bf2f(hv4.x)), f2bf(o1 - bf2f(hv4.y)),
                        f2bf(o2 - bf2f(hv4.z)), f2bf(o3 - bf2f(hv4.w)) };
        ushort2 lv2 = { f2bf(o4 - bf2f(hv2.x)), f2bf(o5 - bf2f(hv2.y)) };
        *reinterpret_cast<ushort4*>(lOut + base + c4) = lv4;
        *reinterpret_cast<ushort2*>(lOut + base + c2) = lv2;
    }
}

extern "C" void kernel_launch(void* const* d_in, const int* in_sizes, int n_in,
                              void* d_out, int out_size, void* d_ws, size_t ws_size,
                              hipStream_t stream)
{
    const float* x    = (const float*)d_in[0];
    const int*   ei   = (const int*)d_in[1];     // int32 (harness ships integer inputs as int32)
    const float* W1   = (const float*)d_in[2];
    const float* as1  = (const float*)d_in[3];
    const float* ad1  = (const float*)d_in[4];
    const float* b1   = (const float*)d_in[5];
    const float* W2   = (const float*)d_in[6];
    const float* as2  = (const float*)d_in[7];
    const float* ad2  = (const float*)d_in[8];
    const float* b2   = (const float*)d_in[9];
    const float* outW = (const float*)d_in[10];
    const float* outb = (const float*)d_in[11];
    float* out = (float*)d_out;

    // ---- workspace layout ----
    u16*   hB   = (u16*)d_ws;                            // bf16 [N,384] gemm out + gather src
    u16*   aggH = hB + (size_t)N_NODES * HC;             // bf16 [N,384]
    u16*   aggL = aggH + (size_t)N_NODES * HC;           // bf16 [N,384] (agg2 lo)
    u16*   xB   = aggH;                                  // alias: xB dead before agg1 writes
    char*  tail = (char*)(aggL + (size_t)N_NODES * HC);
    u16* W1tH = (u16*)tail;                              // [256/8][384][8]
    u16* W1tL = W1tH + (size_t)IN_DIM * HC;
    u16* W2tH = W1tL + (size_t)IN_DIM * HC;              // [384/8][384][8]
    u16* W2tL = W2tH + (size_t)HC * HC;
    u16* WoH  = W2tL + (size_t)HC * HC;                  // [384/8][64][8]
    u16* WoL  = WoH + (size_t)HC * 64;
    float* asrc = (float*)(WoL + (size_t)HC * 64);
    float* adst = asrc + (size_t)N_NODES * HEADS;
    int*   cnt    = (int*)(adst + (size_t)N_NODES * HEADS);
    int*   bucket = cnt + N_NODES;

    hipMemsetAsync(cnt, 0, N_NODES * sizeof(int), stream);
    count_scatter<<<(ET + 255) / 256, 256, 0, stream>>>(ei, cnt, bucket);

    cvt_bf16<<<(N_NODES * IN_DIM / 4 + 255) / 256, 256, 0, stream>>>(x, xB, N_NODES * IN_DIM / 4);
    split_wt<<<(IN_DIM * HC + 255) / 256, 256, 0, stream>>>(W1, W1tH, W1tL, IN_DIM);
    split_wt<<<(HC * HC + 255) / 256, 256, 0, stream>>>(W2, W2tH, W2tL, HC);
    split_wo<<<(HC * 64 + 255) / 256, 256, 0, stream>>>(outW, WoH, WoL);

    dim3 gg(HC / BN, (N_NODES + BM - 1) / BM);   // (3, 391)
    // ---- layer 1 (gemm + fused scores) ----
    gemm_mfma<<<gg, 256, 0, stream>>>(xB, W1tH, W1tL, as1, ad1, asrc, adst, hB, N_NODES, IN_DIM);
    aggregate_kernel<<<(N_NODES + 3) / 4, 256, 0, stream>>>(hB, asrc, adst, cnt, bucket, b1,
                                                            aggH, nullptr);
    // ---- layer 2 (gemm + fused scores) ----
    gemm_mfma<<<gg, 256, 0, stream>>>(aggH, W2tH, W2tL, as2, ad2, asrc, adst, hB, N_NODES, HC);
    aggregate_kernel<<<(N_NODES + 3) / 4, 256, 0, stream>>>(hB, asrc, adst, cnt, bucket, b2,
                                                            aggH, aggL);
    // ---- classifier ----
    out_mfma<<<(N_NODES + OM - 1) / OM, 256, 0, stream>>>(aggH, aggL, WoH, WoL, outb, out);
}